// Round 3
// baseline (5142.337 us; speedup 1.0000x reference)
//
#include <hip/hip_runtime.h>
#include <math.h>

#define TSEQ 512
#define HDIM 512
#define EDIM 512
#define NB   32
#define ROWS 64
#define GATES 2048
#define NWG  32
#define NEGV -1000000000.0f

typedef __attribute__((ext_vector_type(8))) short bf16x8;
typedef __attribute__((ext_vector_type(4))) float f32x4;

__device__ __forceinline__ float sigf(float x){ return 1.0f/(1.0f + __expf(-x)); }

__device__ __forceinline__ unsigned short f2bf(float f){
  unsigned int u = __builtin_bit_cast(unsigned int, f);
  unsigned int r = (u + 0x7fff + ((u>>16)&1)) >> 16;
  return (unsigned short)r;
}

// table[v][j] = sum_k emb[v][k] * W_ih[k][j] + b_lstm[j]   (fp32)
__global__ __launch_bounds__(256) void table_k(const float* __restrict__ emb,
        const float* __restrict__ W_ih, const float* __restrict__ b_lstm,
        float* __restrict__ table){
  int j = blockIdx.x*256 + threadIdx.x;
  int v = blockIdx.y;
  float acc = b_lstm[j];
  #pragma unroll 4
  for(int k=0;k<EDIM;k++) acc = fmaf(emb[v*EDIM+k], W_ih[(size_t)k*GATES+j], acc);
  table[(size_t)v*GATES+j] = acc;
}

// Pre-swizzle W_hh (512 x 2048 fp32) into bf16 B-fragment order for
// mfma_f32_16x16x32_bf16. chunk cid = wg*64 + g*16 + kc; lane l holds
// B[kc*32 + (l>>4)*8 + e][g*512 + wg*16 + (l&15)], e=0..7.
__global__ __launch_bounds__(64) void wprep_k(const float* __restrict__ W_hh,
        unsigned short* __restrict__ Wswz){
  int cid = blockIdx.x;           // 0..2047
  int lane = threadIdx.x;         // 0..63
  int wg = cid>>6, g = (cid>>4)&3, kc = cid&15;
  int col = g*512 + wg*16 + (lane&15);
  int kbase = kc*32 + (lane>>4)*8;
  unsigned short v[8];
  #pragma unroll
  for(int e=0;e<8;e++) v[e] = f2bf(W_hh[(size_t)(kbase+e)*GATES + col]);
  *(uint4*)&Wswz[((size_t)cid*64 + lane)*8] = *(const uint4*)v;
}

__device__ __forceinline__ void gridbar(unsigned* __restrict__ bar, unsigned target, int tid){
  __syncthreads();
  if(tid==0){
    __threadfence();   // release my h_out/hs writes (device scope)
    __hip_atomic_fetch_add(bar, 1u, __ATOMIC_RELAXED, __HIP_MEMORY_SCOPE_AGENT);
    while(__hip_atomic_load(bar, __ATOMIC_RELAXED, __HIP_MEMORY_SCOPE_AGENT) < target)
      __builtin_amdgcn_s_sleep(2);
    __threadfence();   // acquire remote writes
  }
  __syncthreads();
}

// Persistent LSTM: 32 WGs x 512 threads, all 512 steps in one kernel.
// WG wg owns hidden cols jglob = wg*16..+16 (x4 gates), all 64 rows.
// W fragments in registers; c state in registers; h via global double buffer.
__global__ __launch_bounds__(512) void lstm_persist(const int* __restrict__ x, const int* __restrict__ y,
        const float* __restrict__ table, const unsigned short* __restrict__ Wswz,
        unsigned short* __restrict__ hbuf, float* __restrict__ hs,
        unsigned* __restrict__ bar){
  __shared__ float zx[4][64][17];
  int tid = threadIdx.x;
  int wg  = blockIdx.x;
  int wv = tid>>6, lane = tid&63;
  int g = wv>>1, mh = wv&1;

  // this wave's W fragments (gate g), kept in registers for all 512 steps
  bf16x8 wfrag[16];
  {
    const unsigned short* wp = Wswz + (((size_t)wg*64 + (size_t)g*16)*64 + lane)*8;
    #pragma unroll
    for(int kc=0;kc<16;kc++) wfrag[kc] = *(const bf16x8*)(const void*)(wp + (size_t)kc*512);
  }

  int row = tid>>3, jb = (tid&7)*2;
  const int* tokp = (row<NB) ? (x + (size_t)row*TSEQ) : (y + (size_t)(row-NB)*TSEQ);
  int jglob0 = wg*16 + jb;
  // h_out swizzle constants (same for both cells of this thread)
  int kc_o = jglob0>>5;
  int ln_o = (row&15) | (((jglob0>>3)&3)<<4);
  int mt_o = row>>4;
  int e_o  = jglob0&7;
  unsigned short* hop;
  float c0=0.f, c1=0.f;

  for(int s=0;s<TSEQ;s++){
    const unsigned short* h_in = hbuf + (size_t)(s&1)*32768;
    unsigned short* h_out      = hbuf + (size_t)((s+1)&1)*32768;

    f32x4 acc0={0.f,0.f,0.f,0.f}, acc1={0.f,0.f,0.f,0.f};
    #pragma unroll
    for(int kc=0;kc<16;kc++){
      bf16x8 a0 = *(const bf16x8*)(const void*)&h_in[(((mh*2  )*16+kc)*64 + lane)*8];
      bf16x8 a1 = *(const bf16x8*)(const void*)&h_in[(((mh*2+1)*16+kc)*64 + lane)*8];
      acc0 = __builtin_amdgcn_mfma_f32_16x16x32_bf16(a0, wfrag[kc], acc0, 0,0,0);
      acc1 = __builtin_amdgcn_mfma_f32_16x16x32_bf16(a1, wfrag[kc], acc1, 0,0,0);
    }
    #pragma unroll
    for(int q=0;q<4;q++){
      zx[g][(mh*2  )*16 + (lane>>4)*4 + q][lane&15] = acc0[q];
      zx[g][(mh*2+1)*16 + (lane>>4)*4 + q][lane&15] = acc1[q];
    }
    __syncthreads();

    int tok = tokp[s];
    const float* tbl = table + (size_t)tok*GATES;
    float h0, h1;
    {
      float zi  = zx[0][row][jb]   + tbl[jglob0];
      float zf  = zx[1][row][jb]   + tbl[512+jglob0];
      float zg_ = zx[2][row][jb]   + tbl[1024+jglob0];
      float zo  = zx[3][row][jb]   + tbl[1536+jglob0];
      float cn = sigf(zf)*c0 + sigf(zi)*tanhf(zg_);
      h0 = sigf(zo)*tanhf(cn);
      c0 = cn;
    }
    {
      float zi  = zx[0][row][jb+1] + tbl[jglob0+1];
      float zf  = zx[1][row][jb+1] + tbl[512+jglob0+1];
      float zg_ = zx[2][row][jb+1] + tbl[1024+jglob0+1];
      float zo  = zx[3][row][jb+1] + tbl[1536+jglob0+1];
      float cn = sigf(zf)*c1 + sigf(zi)*tanhf(zg_);
      h1 = sigf(zo)*tanhf(cn);
      c1 = cn;
    }
    float2 hv; hv.x = h0; hv.y = h1;
    *(float2*)&hs[(size_t)s*(ROWS*HDIM) + (size_t)row*HDIM + jglob0] = hv;
    unsigned pk = (unsigned)f2bf(h0) | ((unsigned)f2bf(h1)<<16);
    hop = h_out + ((size_t)(mt_o*16+kc_o)*64 + ln_o)*8 + e_o;
    *(unsigned*)hop = pk;

    gridbar(bar, (unsigned)(s+1)*NWG, tid);
  }
}

#define GT 64
#define KT 16
// z[m][n], m = r*512 + t; reads hs slab t (holds h(t+1))
__global__ __launch_bounds__(256) void zproj_k(const float* __restrict__ hs,
        const float* __restrict__ W_out, const float* __restrict__ b_out, float* __restrict__ z){
  __shared__ float As[KT][GT+4];
  __shared__ float Bs[KT][GT+4];
  int m0 = blockIdx.x*GT;
  int n0 = blockIdx.y*GT;
  int tid = threadIdx.x;
  int tm = tid&15, tn = tid>>4;
  float acc[4][4];
  #pragma unroll
  for(int i=0;i<4;i++)
    #pragma unroll
    for(int j=0;j<4;j++) acc[i][j]=0.f;
  for(int k0=0;k0<HDIM;k0+=KT){
    {
      int mloc = tid>>2;
      int kloc = (tid&3)*4;
      int m = m0 + mloc;
      int t = m&511, r = m>>9;
      const float4 av = *(const float4*)&hs[(size_t)t*ROWS*HDIM + (size_t)r*HDIM + k0 + kloc];
      As[kloc+0][mloc]=av.x; As[kloc+1][mloc]=av.y; As[kloc+2][mloc]=av.z; As[kloc+3][mloc]=av.w;
    }
    {
      int kloc = tid>>4;
      int nloc = (tid&15)*4;
      *(float4*)&Bs[kloc][nloc] = *(const float4*)&W_out[(size_t)(k0+kloc)*EDIM + n0 + nloc];
    }
    __syncthreads();
    #pragma unroll
    for(int kk=0;kk<KT;kk++){
      float4 av = *(const float4*)&As[kk][tm*4];
      float4 bv = *(const float4*)&Bs[kk][tn*4];
      float a[4] = {av.x,av.y,av.z,av.w};
      float b[4] = {bv.x,bv.y,bv.z,bv.w};
      #pragma unroll
      for(int i=0;i<4;i++)
        #pragma unroll
        for(int j=0;j<4;j++) acc[i][j] = fmaf(a[i], b[j], acc[i][j]);
    }
    __syncthreads();
  }
  #pragma unroll
  for(int i=0;i<4;i++){
    int m = m0 + tm*4 + i;
    #pragma unroll
    for(int j=0;j<4;j++){
      int n = n0 + tn*4 + j;
      z[(size_t)m*EDIM + n] = acc[i][j] + b_out[n];
    }
  }
}

// theta[b][i][j] = sum_e z[b*512+i][e] * z[(b+32)*512+j][e]   (NT gemm)
__global__ __launch_bounds__(256) void theta_k(const float* __restrict__ z, float* __restrict__ theta){
  __shared__ float As[KT][GT+4];
  __shared__ float Bs[KT][GT+4];
  int m0 = blockIdx.x*GT;
  int n0 = blockIdx.y*GT;
  int b  = blockIdx.z;
  int tid = threadIdx.x;
  int tm = tid&15, tn = tid>>4;
  float acc[4][4];
  #pragma unroll
  for(int i=0;i<4;i++)
    #pragma unroll
    for(int j=0;j<4;j++) acc[i][j]=0.f;
  for(int k0=0;k0<EDIM;k0+=KT){
    {
      int mloc = tid>>2;
      int kloc = (tid&3)*4;
      const float4 av = *(const float4*)&z[((size_t)b*TSEQ + m0+mloc)*EDIM + k0 + kloc];
      As[kloc+0][mloc]=av.x; As[kloc+1][mloc]=av.y; As[kloc+2][mloc]=av.z; As[kloc+3][mloc]=av.w;
    }
    {
      int nloc = tid>>2;
      int kloc = (tid&3)*4;
      const float4 bv = *(const float4*)&z[((size_t)(b+NB)*TSEQ + n0+nloc)*EDIM + k0 + kloc];
      Bs[kloc+0][nloc]=bv.x; Bs[kloc+1][nloc]=bv.y; Bs[kloc+2][nloc]=bv.z; Bs[kloc+3][nloc]=bv.w;
    }
    __syncthreads();
    #pragma unroll
    for(int kk=0;kk<KT;kk++){
      float4 av = *(const float4*)&As[kk][tm*4];
      float4 bv = *(const float4*)&Bs[kk][tn*4];
      float a[4] = {av.x,av.y,av.z,av.w};
      float b2[4] = {bv.x,bv.y,bv.z,bv.w};
      #pragma unroll
      for(int i=0;i<4;i++)
        #pragma unroll
        for(int j=0;j<4;j++) acc[i][j] = fmaf(a[i], b2[j], acc[i][j]);
    }
    __syncthreads();
  }
  #pragma unroll
  for(int i=0;i<4;i++){
    int m = m0 + tm*4 + i;
    #pragma unroll
    for(int j=0;j<4;j++){
      int n = n0 + tn*4 + j;
      theta[((size_t)b*TSEQ + m)*TSEQ + n] = acc[i][j];
    }
  }
}

__global__ __launch_bounds__(256) void mean_k(const float* __restrict__ z, float* __restrict__ zmean){
  int r = blockIdx.x;
  int tid = threadIdx.x;
  for(int ee=tid; ee<EDIM; ee+=256){
    float acc=0.f;
    for(int t=0;t<TSEQ;t++) acc += z[((size_t)r*TSEQ+t)*EDIM+ee];
    zmean[(size_t)r*EDIM+ee] = acc*(1.0f/TSEQ);
  }
}

__global__ __launch_bounds__(256) void gap_k(const float* __restrict__ zmean,
        const float* __restrict__ W_gap, const float* __restrict__ b_gap, float* __restrict__ Aout){
  __shared__ float red[256];
  int b = blockIdx.x;
  int tid = threadIdx.x;
  float acc=0.f;
  for(int i=tid;i<2*EDIM;i+=256){
    float m = (i<EDIM)? zmean[(size_t)b*EDIM+i] : zmean[(size_t)(b+NB)*EDIM + (i-EDIM)];
    acc = fmaf(m, W_gap[i], acc);
  }
  red[tid]=acc; __syncthreads();
  for(int s=128;s>0;s>>=1){ if(tid<s) red[tid]+=red[tid+s]; __syncthreads(); }
  if(tid==0) Aout[b] = red[0] + b_gap[0];
}

// Needleman-Wunsch: one wave per batch; 8 DP cells per lane in registers.
__global__ __launch_bounds__(64) void nw_k(const float* __restrict__ theta,
        const float* __restrict__ Aout, float* __restrict__ out){
  const float L2E = 1.4426950408889634f, LN2 = 0.6931471805599453f;
  int b = blockIdx.x;
  int lane = threadIdx.x;
  float A = Aout[b];
  float p1[8], p2[8];
  #pragma unroll
  for(int i=0;i<8;i++){ p1[i]=NEGV; p2[i]=NEGV; }
  float p1_0 = NEGV, p2_0 = 0.0f;
  const float* th = theta + (size_t)b*TSEQ*TSEQ;
  for(int k=2;k<=1024;k++){
    float pm1 = __shfl_up(p1[7],1);
    float pm2 = __shfl_up(p2[7],1);
    if(lane==0){ pm1 = p1_0; pm2 = p2_0; }
    float td[8];
    #pragma unroll
    for(int cx=0;cx<8;cx++){
      int i = lane*8+1+cx;
      int j = k-i;
      int jc = j<1?1:(j>512?512:j);
      td[cx] = th[(size_t)(i-1)*TSEQ + (jc-1)];
    }
    float cur[8];
    #pragma unroll
    for(int cx=0;cx<8;cx++){
      int i = lane*8+1+cx;
      int j = k-i;
      bool valid = (j>=1)&&(j<=512);
      float a  = (cx==0? pm1 : p1[cx-1]) + A;
      float bb = (cx==0? pm2 : p2[cx-1]);
      float cc = p1[cx] + A;
      float m = fmaxf(fmaxf(a,bb),cc);
      float sum = exp2f((a-m)*L2E) + exp2f((bb-m)*L2E) + exp2f((cc-m)*L2E);
      float v = m + log2f(sum)*LN2;
      cur[cx] = valid ? td[cx] + v : NEGV;
    }
    #pragma unroll
    for(int cx=0;cx<8;cx++){ p2[cx]=p1[cx]; p1[cx]=cur[cx]; }
    p2_0 = p1_0; p1_0 = NEGV;
  }
  if(lane==63) out[b] = p1[7];
}

extern "C" void kernel_launch(void* const* d_in, const int* in_sizes, int n_in,
                              void* d_out, int out_size, void* d_ws, size_t ws_size,
                              hipStream_t stream) {
  (void)in_sizes; (void)n_in; (void)out_size; (void)ws_size;
  const int*   x      = (const int*)d_in[0];
  const int*   y      = (const int*)d_in[1];
  const float* emb    = (const float*)d_in[2];
  const float* W_ih   = (const float*)d_in[3];
  const float* W_hh   = (const float*)d_in[4];
  const float* b_lstm = (const float*)d_in[5];
  const float* W_out  = (const float*)d_in[6];
  const float* b_out  = (const float*)d_in[7];
  const float* W_gap  = (const float*)d_in[8];
  const float* b_gap  = (const float*)d_in[9];
  float* out = (float*)d_out;

  char* ws = (char*)d_ws;
  const size_t OFF_TABLE = 0;                        // 180224
  const size_t OFF_WSWZ  = 184320;                   // 2MB bf16 swizzled W_hh
  const size_t OFF_HSWZ  = OFF_WSWZ + 2097152;       // 2 x 64KB bf16 swizzled h
  const size_t OFF_BAR   = OFF_HSWZ + 131072;        // 4B barrier counter (+pad)
  const size_t OFF_HS    = OFF_BAR + 4096;           // 512*64*512*4 = 64MB
  const size_t OFF_Z     = OFF_HS + 67108864;        // 64MB
  const size_t OFF_THETA = OFF_Z + 67108864;         // 32MB
  const size_t OFF_ZMEAN = OFF_THETA + 33554432;     // 128KB
  const size_t OFF_AOUT  = OFF_ZMEAN + 131072;       // 128B
  float* table = (float*)(ws + OFF_TABLE);
  unsigned short* Wswz = (unsigned short*)(ws + OFF_WSWZ);
  unsigned short* hswz = (unsigned short*)(ws + OFF_HSWZ);
  unsigned* bar = (unsigned*)(ws + OFF_BAR);
  float* hs    = (float*)(ws + OFF_HS);
  float* z     = (float*)(ws + OFF_Z);
  float* theta = (float*)(ws + OFF_THETA);
  float* zmean = (float*)(ws + OFF_ZMEAN);
  float* Aout  = (float*)(ws + OFF_AOUT);

  hipMemsetAsync(hswz, 0, 65536, stream);            // h(0) = 0 (buffer 0)
  hipMemsetAsync(bar,  0, 4096,  stream);            // barrier counter

  table_k<<<dim3(8,22), 256, 0, stream>>>(emb, W_ih, b_lstm, table);
  wprep_k<<<2048, 64, 0, stream>>>(W_hh, Wswz);
  lstm_persist<<<NWG, 512, 0, stream>>>(x, y, table, Wswz, hswz, hs, bar);
  zproj_k<<<dim3(512,8), 256, 0, stream>>>(hs, W_out, b_out, z);
  theta_k<<<dim3(8,8,32), 256, 0, stream>>>(z, theta);
  mean_k<<<64, 256, 0, stream>>>(z, zmean);
  gap_k<<<32, 256, 0, stream>>>(zmean, W_gap, b_gap, Aout);
  nw_k<<<32, 64, 0, stream>>>(theta, Aout, out);
}

// Round 4
// 4720.176 us; speedup vs baseline: 1.0894x; 1.0894x over previous
//
#include <hip/hip_runtime.h>
#include <math.h>

#define TSEQ 512
#define HDIM 512
#define EDIM 512
#define NB   32
#define ROWS 64
#define GATES 2048
#define NWG  32
#define NEGV -1000000000.0f

typedef __attribute__((ext_vector_type(8))) short bf16x8;
typedef __attribute__((ext_vector_type(4))) float f32x4;

struct u64x2 { unsigned long long lo, hi; };

__device__ __forceinline__ float sigf(float x){ return 1.0f/(1.0f + __expf(-x)); }

// overflow-safe fast tanh: t = e^{-2|x|} in (0,1], r = (1-t)/(1+t), sign restore
__device__ __forceinline__ float tanhfast(float x){
  float t = __expf(-2.0f*fabsf(x));
  float r = (1.0f - t)/(1.0f + t);
  return copysignf(r, x);
}

__device__ __forceinline__ unsigned short f2bf(float f){
  unsigned int u = __builtin_bit_cast(unsigned int, f);
  unsigned int r = (u + 0x7fff + ((u>>16)&1)) >> 16;
  return (unsigned short)r;
}

// table[v][j] = sum_k emb[v][k] * W_ih[k][j] + b_lstm[j]   (fp32)
__global__ __launch_bounds__(256) void table_k(const float* __restrict__ emb,
        const float* __restrict__ W_ih, const float* __restrict__ b_lstm,
        float* __restrict__ table){
  int j = blockIdx.x*256 + threadIdx.x;
  int v = blockIdx.y;
  float acc = b_lstm[j];
  #pragma unroll 4
  for(int k=0;k<EDIM;k++) acc = fmaf(emb[v*EDIM+k], W_ih[(size_t)k*GATES+j], acc);
  table[(size_t)v*GATES+j] = acc;
}

// Pre-swizzle W_hh into bf16 B-fragment order for mfma_f32_16x16x32_bf16.
__global__ __launch_bounds__(64) void wprep_k(const float* __restrict__ W_hh,
        unsigned short* __restrict__ Wswz){
  int cid = blockIdx.x;           // 0..2047
  int lane = threadIdx.x;         // 0..63
  int wg = cid>>6, g = (cid>>4)&3, kc = cid&15;
  int col = g*512 + wg*16 + (lane&15);
  int kbase = kc*32 + (lane>>4)*8;
  unsigned short v[8];
  #pragma unroll
  for(int e=0;e<8;e++) v[e] = f2bf(W_hh[(size_t)(kbase+e)*GATES + col]);
  *(uint4*)&Wswz[((size_t)cid*64 + lane)*8] = *(const uint4*)v;
}

// Persistent LSTM: 32 WGs x 512 threads. W in registers, c in registers,
// h exchanged via agent-scope (cache-bypassing) loads/stores; no threadfence.
__global__ __launch_bounds__(512) void lstm_persist(const int* __restrict__ x, const int* __restrict__ y,
        const float* __restrict__ table, const unsigned short* __restrict__ Wswz,
        unsigned short* __restrict__ hbuf, float* __restrict__ hs,
        unsigned* __restrict__ bar){
  __shared__ float zx[4][64][17];
  int tid = threadIdx.x;
  int wg  = blockIdx.x;
  int wv = tid>>6, lane = tid&63;
  int g = wv>>1, mh = wv&1;

  // this wave's W fragments (gate g), in registers for all 512 steps
  bf16x8 wfrag[16];
  {
    const unsigned short* wp = Wswz + (((size_t)wg*64 + (size_t)g*16)*64 + lane)*8;
    #pragma unroll
    for(int kc=0;kc<16;kc++) wfrag[kc] = *(const bf16x8*)(const void*)(wp + (size_t)kc*512);
  }

  int row = tid>>3, jb = (tid&7)*2;
  const int* tokp = (row<NB) ? (x + (size_t)row*TSEQ) : (y + (size_t)(row-NB)*TSEQ);
  int jglob0 = wg*16 + jb;
  int kc_o = jglob0>>5;
  int ln_o = (row&15) | (((jglob0>>3)&3)<<4);
  int mt_o = row>>4;
  int e_o  = jglob0&7;
  float c0=0.f, c1=0.f;

  for(int s=0;s<TSEQ;s++){
    const unsigned short* h_in = hbuf + (size_t)(s&1)*32768;
    unsigned short* h_out      = hbuf + (size_t)((s+1)&1)*32768;

    // ---- MFMA phase: agent-scope (sc0 sc1) loads of h fragments ----
    f32x4 accA0={0.f,0.f,0.f,0.f}, accA1={0.f,0.f,0.f,0.f};
    f32x4 accB0={0.f,0.f,0.f,0.f}, accB1={0.f,0.f,0.f,0.f};
    #pragma unroll
    for(int kc=0;kc<16;kc++){
      const unsigned long long* p0 = (const unsigned long long*)(const void*)&h_in[(((mh*2  )*16+kc)*64 + lane)*8];
      const unsigned long long* p1 = (const unsigned long long*)(const void*)&h_in[(((mh*2+1)*16+kc)*64 + lane)*8];
      unsigned long long a0l = __hip_atomic_load(p0,   __ATOMIC_RELAXED, __HIP_MEMORY_SCOPE_AGENT);
      unsigned long long a0h = __hip_atomic_load(p0+1, __ATOMIC_RELAXED, __HIP_MEMORY_SCOPE_AGENT);
      unsigned long long a1l = __hip_atomic_load(p1,   __ATOMIC_RELAXED, __HIP_MEMORY_SCOPE_AGENT);
      unsigned long long a1h = __hip_atomic_load(p1+1, __ATOMIC_RELAXED, __HIP_MEMORY_SCOPE_AGENT);
      bf16x8 a0 = __builtin_bit_cast(bf16x8, u64x2{a0l, a0h});
      bf16x8 a1 = __builtin_bit_cast(bf16x8, u64x2{a1l, a1h});
      if(kc<8){
        accA0 = __builtin_amdgcn_mfma_f32_16x16x32_bf16(a0, wfrag[kc], accA0, 0,0,0);
        accA1 = __builtin_amdgcn_mfma_f32_16x16x32_bf16(a1, wfrag[kc], accA1, 0,0,0);
      }else{
        accB0 = __builtin_amdgcn_mfma_f32_16x16x32_bf16(a0, wfrag[kc], accB0, 0,0,0);
        accB1 = __builtin_amdgcn_mfma_f32_16x16x32_bf16(a1, wfrag[kc], accB1, 0,0,0);
      }
    }
    f32x4 acc0 = accA0 + accB0;
    f32x4 acc1 = accA1 + accB1;
    #pragma unroll
    for(int q=0;q<4;q++){
      zx[g][(mh*2  )*16 + (lane>>4)*4 + q][lane&15] = acc0[q];
      zx[g][(mh*2+1)*16 + (lane>>4)*4 + q][lane&15] = acc1[q];
    }
    __syncthreads();

    // ---- gate phase (table/tokens stay cached — no invalidation anywhere) ----
    int tok = tokp[s];
    const float* tbl = table + (size_t)tok*GATES;
    float h0, h1;
    {
      float zi  = zx[0][row][jb]   + tbl[jglob0];
      float zf  = zx[1][row][jb]   + tbl[512+jglob0];
      float zg_ = zx[2][row][jb]   + tbl[1024+jglob0];
      float zo  = zx[3][row][jb]   + tbl[1536+jglob0];
      float cn = sigf(zf)*c0 + sigf(zi)*tanhfast(zg_);
      h0 = sigf(zo)*tanhfast(cn);
      c0 = cn;
    }
    {
      float zi  = zx[0][row][jb+1] + tbl[jglob0+1];
      float zf  = zx[1][row][jb+1] + tbl[512+jglob0+1];
      float zg_ = zx[2][row][jb+1] + tbl[1024+jglob0+1];
      float zo  = zx[3][row][jb+1] + tbl[1536+jglob0+1];
      float cn = sigf(zf)*c1 + sigf(zi)*tanhfast(zg_);
      h1 = sigf(zo)*tanhfast(cn);
      c1 = cn;
    }
    // publish h (agent-scope store, write-through to coherence point)
    unsigned pk = (unsigned)f2bf(h0) | ((unsigned)f2bf(h1)<<16);
    unsigned* hop = (unsigned*)(void*)(h_out + ((size_t)(mt_o*16+kc_o)*64 + ln_o)*8 + e_o);
    __hip_atomic_store(hop, pk, __ATOMIC_RELAXED, __HIP_MEMORY_SCOPE_AGENT);

    __syncthreads();   // drains vmcnt(0) for every wave -> all h stores at coherence point
    if(tid==0)
      __hip_atomic_fetch_add(bar, 1u, __ATOMIC_RELAXED, __HIP_MEMORY_SCOPE_AGENT);

    // off-critical-path: cached hs store (consumed only after kernel end)
    float2 hv; hv.x = h0; hv.y = h1;
    *(float2*)&hs[(size_t)s*(ROWS*HDIM) + (size_t)row*HDIM + jglob0] = hv;

    if(tid==0){
      unsigned target = (unsigned)(s+1)*NWG;
      while(__hip_atomic_load(bar, __ATOMIC_RELAXED, __HIP_MEMORY_SCOPE_AGENT) < target)
        __builtin_amdgcn_s_sleep(1);
    }
    asm volatile("" ::: "memory");
    __syncthreads();
  }
}

#define GT 64
#define KT 16
// z[m][n], m = r*512 + t; reads hs slab t (holds h(t+1))
__global__ __launch_bounds__(256) void zproj_k(const float* __restrict__ hs,
        const float* __restrict__ W_out, const float* __restrict__ b_out, float* __restrict__ z){
  __shared__ float As[KT][GT+4];
  __shared__ float Bs[KT][GT+4];
  int m0 = blockIdx.x*GT;
  int n0 = blockIdx.y*GT;
  int tid = threadIdx.x;
  int tm = tid&15, tn = tid>>4;
  float acc[4][4];
  #pragma unroll
  for(int i=0;i<4;i++)
    #pragma unroll
    for(int j=0;j<4;j++) acc[i][j]=0.f;
  for(int k0=0;k0<HDIM;k0+=KT){
    {
      int mloc = tid>>2;
      int kloc = (tid&3)*4;
      int m = m0 + mloc;
      int t = m&511, r = m>>9;
      const float4 av = *(const float4*)&hs[(size_t)t*ROWS*HDIM + (size_t)r*HDIM + k0 + kloc];
      As[kloc+0][mloc]=av.x; As[kloc+1][mloc]=av.y; As[kloc+2][mloc]=av.z; As[kloc+3][mloc]=av.w;
    }
    {
      int kloc = tid>>4;
      int nloc = (tid&15)*4;
      *(float4*)&Bs[kloc][nloc] = *(const float4*)&W_out[(size_t)(k0+kloc)*EDIM + n0 + nloc];
    }
    __syncthreads();
    #pragma unroll
    for(int kk=0;kk<KT;kk++){
      float4 av = *(const float4*)&As[kk][tm*4];
      float4 bv = *(const float4*)&Bs[kk][tn*4];
      float a[4] = {av.x,av.y,av.z,av.w};
      float b[4] = {bv.x,bv.y,bv.z,bv.w};
      #pragma unroll
      for(int i=0;i<4;i++)
        #pragma unroll
        for(int j=0;j<4;j++) acc[i][j] = fmaf(a[i], b[j], acc[i][j]);
    }
    __syncthreads();
  }
  #pragma unroll
  for(int i=0;i<4;i++){
    int m = m0 + tm*4 + i;
    #pragma unroll
    for(int j=0;j<4;j++){
      int n = n0 + tn*4 + j;
      z[(size_t)m*EDIM + n] = acc[i][j] + b_out[n];
    }
  }
}

// theta[b][i][j] = sum_e z[b*512+i][e] * z[(b+32)*512+j][e]   (NT gemm)
__global__ __launch_bounds__(256) void theta_k(const float* __restrict__ z, float* __restrict__ theta){
  __shared__ float As[KT][GT+4];
  __shared__ float Bs[KT][GT+4];
  int m0 = blockIdx.x*GT;
  int n0 = blockIdx.y*GT;
  int b  = blockIdx.z;
  int tid = threadIdx.x;
  int tm = tid&15, tn = tid>>4;
  float acc[4][4];
  #pragma unroll
  for(int i=0;i<4;i++)
    #pragma unroll
    for(int j=0;j<4;j++) acc[i][j]=0.f;
  for(int k0=0;k0<EDIM;k0+=KT){
    {
      int mloc = tid>>2;
      int kloc = (tid&3)*4;
      const float4 av = *(const float4*)&z[((size_t)b*TSEQ + m0+mloc)*EDIM + k0 + kloc];
      As[kloc+0][mloc]=av.x; As[kloc+1][mloc]=av.y; As[kloc+2][mloc]=av.z; As[kloc+3][mloc]=av.w;
    }
    {
      int nloc = tid>>2;
      int kloc = (tid&3)*4;
      const float4 bv = *(const float4*)&z[((size_t)(b+NB)*TSEQ + n0+nloc)*EDIM + k0 + kloc];
      Bs[kloc+0][nloc]=bv.x; Bs[kloc+1][nloc]=bv.y; Bs[kloc+2][nloc]=bv.z; Bs[kloc+3][nloc]=bv.w;
    }
    __syncthreads();
    #pragma unroll
    for(int kk=0;kk<KT;kk++){
      float4 av = *(const float4*)&As[kk][tm*4];
      float4 bv = *(const float4*)&Bs[kk][tn*4];
      float a[4] = {av.x,av.y,av.z,av.w};
      float b2[4] = {bv.x,bv.y,bv.z,bv.w};
      #pragma unroll
      for(int i=0;i<4;i++)
        #pragma unroll
        for(int j=0;j<4;j++) acc[i][j] = fmaf(a[i], b2[j], acc[i][j]);
    }
    __syncthreads();
  }
  #pragma unroll
  for(int i=0;i<4;i++){
    int m = m0 + tm*4 + i;
    #pragma unroll
    for(int j=0;j<4;j++){
      int n = n0 + tn*4 + j;
      theta[((size_t)b*TSEQ + m)*TSEQ + n] = acc[i][j];
    }
  }
}

__global__ __launch_bounds__(256) void mean_k(const float* __restrict__ z, float* __restrict__ zmean){
  int r = blockIdx.x;
  int tid = threadIdx.x;
  for(int ee=tid; ee<EDIM; ee+=256){
    float acc=0.f;
    for(int t=0;t<TSEQ;t++) acc += z[((size_t)r*TSEQ+t)*EDIM+ee];
    zmean[(size_t)r*EDIM+ee] = acc*(1.0f/TSEQ);
  }
}

__global__ __launch_bounds__(256) void gap_k(const float* __restrict__ zmean,
        const float* __restrict__ W_gap, const float* __restrict__ b_gap, float* __restrict__ Aout){
  __shared__ float red[256];
  int b = blockIdx.x;
  int tid = threadIdx.x;
  float acc=0.f;
  for(int i=tid;i<2*EDIM;i+=256){
    float m = (i<EDIM)? zmean[(size_t)b*EDIM+i] : zmean[(size_t)(b+NB)*EDIM + (i-EDIM)];
    acc = fmaf(m, W_gap[i], acc);
  }
  red[tid]=acc; __syncthreads();
  for(int s=128;s>0;s>>=1){ if(tid<s) red[tid]+=red[tid+s]; __syncthreads(); }
  if(tid==0) Aout[b] = red[0] + b_gap[0];
}

// Needleman-Wunsch: one wave per batch; 8 DP cells per lane in registers.
__global__ __launch_bounds__(64) void nw_k(const float* __restrict__ theta,
        const float* __restrict__ Aout, float* __restrict__ out){
  const float L2E = 1.4426950408889634f, LN2 = 0.6931471805599453f;
  int b = blockIdx.x;
  int lane = threadIdx.x;
  float A = Aout[b];
  float p1[8], p2[8];
  #pragma unroll
  for(int i=0;i<8;i++){ p1[i]=NEGV; p2[i]=NEGV; }
  float p1_0 = NEGV, p2_0 = 0.0f;
  const float* th = theta + (size_t)b*TSEQ*TSEQ;
  for(int k=2;k<=1024;k++){
    float pm1 = __shfl_up(p1[7],1);
    float pm2 = __shfl_up(p2[7],1);
    if(lane==0){ pm1 = p1_0; pm2 = p2_0; }
    float td[8];
    #pragma unroll
    for(int cx=0;cx<8;cx++){
      int i = lane*8+1+cx;
      int j = k-i;
      int jc = j<1?1:(j>512?512:j);
      td[cx] = th[(size_t)(i-1)*TSEQ + (jc-1)];
    }
    float cur[8];
    #pragma unroll
    for(int cx=0;cx<8;cx++){
      int i = lane*8+1+cx;
      int j = k-i;
      bool valid = (j>=1)&&(j<=512);
      float a  = (cx==0? pm1 : p1[cx-1]) + A;
      float bb = (cx==0? pm2 : p2[cx-1]);
      float cc = p1[cx] + A;
      float m = fmaxf(fmaxf(a,bb),cc);
      float sum = exp2f((a-m)*L2E) + exp2f((bb-m)*L2E) + exp2f((cc-m)*L2E);
      float v = m + log2f(sum)*LN2;
      cur[cx] = valid ? td[cx] + v : NEGV;
    }
    #pragma unroll
    for(int cx=0;cx<8;cx++){ p2[cx]=p1[cx]; p1[cx]=cur[cx]; }
    p2_0 = p1_0; p1_0 = NEGV;
  }
  if(lane==63) out[b] = p1[7];
}

extern "C" void kernel_launch(void* const* d_in, const int* in_sizes, int n_in,
                              void* d_out, int out_size, void* d_ws, size_t ws_size,
                              hipStream_t stream) {
  (void)in_sizes; (void)n_in; (void)out_size; (void)ws_size;
  const int*   x      = (const int*)d_in[0];
  const int*   y      = (const int*)d_in[1];
  const float* emb    = (const float*)d_in[2];
  const float* W_ih   = (const float*)d_in[3];
  const float* W_hh   = (const float*)d_in[4];
  const float* b_lstm = (const float*)d_in[5];
  const float* W_out  = (const float*)d_in[6];
  const float* b_out  = (const float*)d_in[7];
  const float* W_gap  = (const float*)d_in[8];
  const float* b_gap  = (const float*)d_in[9];
  float* out = (float*)d_out;

  char* ws = (char*)d_ws;
  const size_t OFF_TABLE = 0;                        // 180224
  const size_t OFF_WSWZ  = 184320;                   // 2MB bf16 swizzled W_hh
  const size_t OFF_HSWZ  = OFF_WSWZ + 2097152;       // 2 x 64KB bf16 swizzled h
  const size_t OFF_BAR   = OFF_HSWZ + 131072;        // 4B barrier counter (+pad)
  const size_t OFF_HS    = OFF_BAR + 4096;           // 64MB
  const size_t OFF_Z     = OFF_HS + 67108864;        // 64MB
  const size_t OFF_THETA = OFF_Z + 67108864;         // 32MB
  const size_t OFF_ZMEAN = OFF_THETA + 33554432;     // 128KB
  const size_t OFF_AOUT  = OFF_ZMEAN + 131072;       // 128B
  float* table = (float*)(ws + OFF_TABLE);
  unsigned short* Wswz = (unsigned short*)(ws + OFF_WSWZ);
  unsigned short* hswz = (unsigned short*)(ws + OFF_HSWZ);
  unsigned* bar = (unsigned*)(ws + OFF_BAR);
  float* hs    = (float*)(ws + OFF_HS);
  float* z     = (float*)(ws + OFF_Z);
  float* theta = (float*)(ws + OFF_THETA);
  float* zmean = (float*)(ws + OFF_ZMEAN);
  float* Aout  = (float*)(ws + OFF_AOUT);

  hipMemsetAsync(hswz, 0, 65536, stream);            // h(0) = 0 (buffer 0)
  hipMemsetAsync(bar,  0, 4096,  stream);            // barrier counter

  table_k<<<dim3(8,22), 256, 0, stream>>>(emb, W_ih, b_lstm, table);
  wprep_k<<<2048, 64, 0, stream>>>(W_hh, Wswz);
  lstm_persist<<<NWG, 512, 0, stream>>>(x, y, table, Wswz, hswz, hs, bar);
  zproj_k<<<dim3(512,8), 256, 0, stream>>>(hs, W_out, b_out, z);
  theta_k<<<dim3(8,8,32), 256, 0, stream>>>(z, theta);
  mean_k<<<64, 256, 0, stream>>>(z, zmean);
  gap_k<<<32, 256, 0, stream>>>(zmean, W_gap, b_gap, Aout);
  nw_k<<<32, 64, 0, stream>>>(theta, Aout, out);
}

// Round 5
// 3213.059 us; speedup vs baseline: 1.6004x; 1.4691x over previous
//
#include <hip/hip_runtime.h>
#include <math.h>

#define TSEQ 512
#define HDIM 512
#define EDIM 512
#define NB   32
#define ROWS 64
#define GATES 2048
#define NWG  32
#define NEGV -1000000000.0f

typedef __attribute__((ext_vector_type(8))) short bf16x8;
typedef __attribute__((ext_vector_type(4))) float f32x4;

__device__ __forceinline__ float sigf(float x){ return 1.0f/(1.0f + __expf(-x)); }

// overflow-safe fast tanh
__device__ __forceinline__ float tanhfast(float x){
  float t = __expf(-2.0f*fabsf(x));
  float r = (1.0f - t)/(1.0f + t);
  return copysignf(r, x);
}

__device__ __forceinline__ unsigned short f2bf(float f){
  unsigned int u = __builtin_bit_cast(unsigned int, f);
  unsigned int r = (u + 0x7fff + ((u>>16)&1)) >> 16;
  return (unsigned short)r;
}

// table[v][j] = sum_k emb[v][k] * W_ih[k][j] + b_lstm[j]   (fp32)
__global__ __launch_bounds__(256) void table_k(const float* __restrict__ emb,
        const float* __restrict__ W_ih, const float* __restrict__ b_lstm,
        float* __restrict__ table){
  int j = blockIdx.x*256 + threadIdx.x;
  int v = blockIdx.y;
  float acc = b_lstm[j];
  #pragma unroll 4
  for(int k=0;k<EDIM;k++) acc = fmaf(emb[v*EDIM+k], W_ih[(size_t)k*GATES+j], acc);
  table[(size_t)v*GATES+j] = acc;
}

// Pre-swizzle W_hh into bf16 B-fragment order for mfma_f32_16x16x32_bf16.
__global__ __launch_bounds__(64) void wprep_k(const float* __restrict__ W_hh,
        unsigned short* __restrict__ Wswz){
  int cid = blockIdx.x;           // 0..2047
  int lane = threadIdx.x;         // 0..63
  int wg = cid>>6, g = (cid>>4)&3, kc = cid&15;
  int col = g*512 + wg*16 + (lane&15);
  int kbase = kc*32 + (lane>>4)*8;
  unsigned short v[8];
  #pragma unroll
  for(int e=0;e<8;e++) v[e] = f2bf(W_hh[(size_t)(kbase+e)*GATES + col]);
  *(uint4*)&Wswz[((size_t)cid*64 + lane)*8] = *(const uint4*)v;
}

// Persistent LSTM: 32 WGs x 512 threads. W in registers, c in registers.
// h exchange: agent-scope publish -> per-WG flag -> LDS-staged bulk load.
__global__ __launch_bounds__(512,2) void lstm_persist(const int* __restrict__ x, const int* __restrict__ y,
        const float* __restrict__ table, const unsigned short* __restrict__ Wswz,
        unsigned short* __restrict__ hbuf, float* __restrict__ hs,
        unsigned* __restrict__ flags){
  __shared__ unsigned short hA[32768];   // 64KB staged h fragments (linear copy)
  __shared__ float zx[4][64][17];
  int tid = threadIdx.x;
  int wg  = blockIdx.x;
  int wv = tid>>6, lane = tid&63;
  int g = wv>>1, mh = wv&1;

  // this wave's W fragments (gate g), in registers for all 512 steps
  bf16x8 wfrag[16];
  {
    const unsigned short* wp = Wswz + (((size_t)wg*64 + (size_t)g*16)*64 + lane)*8;
    #pragma unroll
    for(int kc=0;kc<16;kc++) wfrag[kc] = *(const bf16x8*)(const void*)(wp + (size_t)kc*512);
  }

  int row = tid>>3, jb = (tid&7)*2;
  const int* tokp = (row<NB) ? (x + (size_t)row*TSEQ) : (y + (size_t)(row-NB)*TSEQ);
  int jglob0 = wg*16 + jb;
  int kc_o = jglob0>>5;
  int ln_o = (row&15) | (((jglob0>>3)&3)<<4);
  int mt_o = row>>4;
  int e_o  = jglob0&7;
  float c0=0.f, c1=0.f;

  unsigned va0 = tid*16;   // staging voffsets (bytes), +i*8192
  for(int s=0;s<TSEQ;s++){
    const unsigned short* h_in = hbuf + (size_t)(s&1)*32768;
    unsigned short* h_out      = hbuf + (size_t)((s+1)&1)*32768;

    // ---- stage full 64KB h into LDS: 8 x dwordx4 agent loads per thread ----
    {
      uint4 t0,t1,t2,t3,t4,t5,t6,t7;
      asm volatile(
        "global_load_dwordx4 %[t0], %[a0], %[sb] sc0 sc1\n\t"
        "global_load_dwordx4 %[t1], %[a1], %[sb] sc0 sc1\n\t"
        "global_load_dwordx4 %[t2], %[a2], %[sb] sc0 sc1\n\t"
        "global_load_dwordx4 %[t3], %[a3], %[sb] sc0 sc1\n\t"
        "global_load_dwordx4 %[t4], %[a4], %[sb] sc0 sc1\n\t"
        "global_load_dwordx4 %[t5], %[a5], %[sb] sc0 sc1\n\t"
        "global_load_dwordx4 %[t6], %[a6], %[sb] sc0 sc1\n\t"
        "global_load_dwordx4 %[t7], %[a7], %[sb] sc0 sc1\n\t"
        "s_waitcnt vmcnt(0)"
        : [t0]"=v"(t0),[t1]"=v"(t1),[t2]"=v"(t2),[t3]"=v"(t3),
          [t4]"=v"(t4),[t5]"=v"(t5),[t6]"=v"(t6),[t7]"=v"(t7)
        : [a0]"v"(va0),[a1]"v"(va0+8192u),[a2]"v"(va0+16384u),[a3]"v"(va0+24576u),
          [a4]"v"(va0+32768u),[a5]"v"(va0+40960u),[a6]"v"(va0+49152u),[a7]"v"(va0+57344u),
          [sb]"s"((const void*)h_in)
        : "memory");
      char* hb = (char*)hA;
      *(uint4*)(hb + tid*16          ) = t0;
      *(uint4*)(hb + tid*16 +  8192  ) = t1;
      *(uint4*)(hb + tid*16 + 16384  ) = t2;
      *(uint4*)(hb + tid*16 + 24576  ) = t3;
      *(uint4*)(hb + tid*16 + 32768  ) = t4;
      *(uint4*)(hb + tid*16 + 40960  ) = t5;
      *(uint4*)(hb + tid*16 + 49152  ) = t6;
      *(uint4*)(hb + tid*16 + 57344  ) = t7;
    }
    __syncthreads();

    // ---- MFMA phase from LDS (conflict-free stride-16B reads) ----
    f32x4 accA0={0.f,0.f,0.f,0.f}, accA1={0.f,0.f,0.f,0.f};
    f32x4 accB0={0.f,0.f,0.f,0.f}, accB1={0.f,0.f,0.f,0.f};
    #pragma unroll
    for(int kc=0;kc<16;kc++){
      bf16x8 a0 = *(const bf16x8*)(const void*)&hA[(((mh*2  )*16+kc)*64 + lane)*8];
      bf16x8 a1 = *(const bf16x8*)(const void*)&hA[(((mh*2+1)*16+kc)*64 + lane)*8];
      if(kc<8){
        accA0 = __builtin_amdgcn_mfma_f32_16x16x32_bf16(a0, wfrag[kc], accA0, 0,0,0);
        accA1 = __builtin_amdgcn_mfma_f32_16x16x32_bf16(a1, wfrag[kc], accA1, 0,0,0);
      }else{
        accB0 = __builtin_amdgcn_mfma_f32_16x16x32_bf16(a0, wfrag[kc], accB0, 0,0,0);
        accB1 = __builtin_amdgcn_mfma_f32_16x16x32_bf16(a1, wfrag[kc], accB1, 0,0,0);
      }
    }
    f32x4 acc0 = accA0 + accB0;
    f32x4 acc1 = accA1 + accB1;
    __syncthreads();   // hA reads done before zx overwrite? (zx separate) -- keep for phase order
    #pragma unroll
    for(int q=0;q<4;q++){
      zx[g][(mh*2  )*16 + (lane>>4)*4 + q][lane&15] = acc0[q];
      zx[g][(mh*2+1)*16 + (lane>>4)*4 + q][lane&15] = acc1[q];
    }
    __syncthreads();

    // ---- gate phase (cached reads; no cache invalidation anywhere) ----
    int tok = tokp[s];
    const float* tbl = table + (size_t)tok*GATES;
    float h0, h1;
    {
      float zi  = zx[0][row][jb]   + tbl[jglob0];
      float zf  = zx[1][row][jb]   + tbl[512+jglob0];
      float zg_ = zx[2][row][jb]   + tbl[1024+jglob0];
      float zo  = zx[3][row][jb]   + tbl[1536+jglob0];
      float cn = sigf(zf)*c0 + sigf(zi)*tanhfast(zg_);
      h0 = sigf(zo)*tanhfast(cn);
      c0 = cn;
    }
    {
      float zi  = zx[0][row][jb+1] + tbl[jglob0+1];
      float zf  = zx[1][row][jb+1] + tbl[512+jglob0+1];
      float zg_ = zx[2][row][jb+1] + tbl[1024+jglob0+1];
      float zo  = zx[3][row][jb+1] + tbl[1536+jglob0+1];
      float cn = sigf(zf)*c1 + sigf(zi)*tanhfast(zg_);
      h1 = sigf(zo)*tanhfast(cn);
      c1 = cn;
    }
    // publish h (agent-scope store to coherence point)
    unsigned pk = (unsigned)f2bf(h0) | ((unsigned)f2bf(h1)<<16);
    unsigned* hop = (unsigned*)(void*)(h_out + ((size_t)(mt_o*16+kc_o)*64 + ln_o)*8 + e_o);
    __hip_atomic_store(hop, pk, __ATOMIC_RELAXED, __HIP_MEMORY_SCOPE_AGENT);

    __syncthreads();   // drains vmcnt(0) for all waves -> h stores visible at L3
    if(tid==0)
      __hip_atomic_store(&flags[wg*32], (unsigned)(s+1), __ATOMIC_RELAXED, __HIP_MEMORY_SCOPE_AGENT);

    // off-critical-path cached hs store (overlaps flag propagation)
    float2 hv; hv.x = h0; hv.y = h1;
    *(float2*)&hs[(size_t)s*(ROWS*HDIM) + (size_t)row*HDIM + jglob0] = hv;

    // distributed flag wait: wave 0 polls all 32 flags in parallel
    if(wv==0){
      const unsigned* fp = flags + (size_t)(lane&31)*32;
      while(__all((int)(__hip_atomic_load(fp, __ATOMIC_RELAXED, __HIP_MEMORY_SCOPE_AGENT) >= (unsigned)(s+1))) == 0){ }
    }
    __syncthreads();
  }
}

#define GT 64
#define KT 16
// z[m][n], m = r*512 + t; reads hs slab t (holds h(t+1))
__global__ __launch_bounds__(256) void zproj_k(const float* __restrict__ hs,
        const float* __restrict__ W_out, const float* __restrict__ b_out, float* __restrict__ z){
  __shared__ float As[KT][GT+4];
  __shared__ float Bs[KT][GT+4];
  int m0 = blockIdx.x*GT;
  int n0 = blockIdx.y*GT;
  int tid = threadIdx.x;
  int tm = tid&15, tn = tid>>4;
  float acc[4][4];
  #pragma unroll
  for(int i=0;i<4;i++)
    #pragma unroll
    for(int j=0;j<4;j++) acc[i][j]=0.f;
  for(int k0=0;k0<HDIM;k0+=KT){
    {
      int mloc = tid>>2;
      int kloc = (tid&3)*4;
      int m = m0 + mloc;
      int t = m&511, r = m>>9;
      const float4 av = *(const float4*)&hs[(size_t)t*ROWS*HDIM + (size_t)r*HDIM + k0 + kloc];
      As[kloc+0][mloc]=av.x; As[kloc+1][mloc]=av.y; As[kloc+2][mloc]=av.z; As[kloc+3][mloc]=av.w;
    }
    {
      int kloc = tid>>4;
      int nloc = (tid&15)*4;
      *(float4*)&Bs[kloc][nloc] = *(const float4*)&W_out[(size_t)(k0+kloc)*EDIM + n0 + nloc];
    }
    __syncthreads();
    #pragma unroll
    for(int kk=0;kk<KT;kk++){
      float4 av = *(const float4*)&As[kk][tm*4];
      float4 bv = *(const float4*)&Bs[kk][tn*4];
      float a[4] = {av.x,av.y,av.z,av.w};
      float b[4] = {bv.x,bv.y,bv.z,bv.w};
      #pragma unroll
      for(int i=0;i<4;i++)
        #pragma unroll
        for(int j=0;j<4;j++) acc[i][j] = fmaf(a[i], b[j], acc[i][j]);
    }
    __syncthreads();
  }
  #pragma unroll
  for(int i=0;i<4;i++){
    int m = m0 + tm*4 + i;
    #pragma unroll
    for(int j=0;j<4;j++){
      int n = n0 + tn*4 + j;
      z[(size_t)m*EDIM + n] = acc[i][j] + b_out[n];
    }
  }
}

// theta[b][i][j] = sum_e z[b*512+i][e] * z[(b+32)*512+j][e]   (NT gemm)
__global__ __launch_bounds__(256) void theta_k(const float* __restrict__ z, float* __restrict__ theta){
  __shared__ float As[KT][GT+4];
  __shared__ float Bs[KT][GT+4];
  int m0 = blockIdx.x*GT;
  int n0 = blockIdx.y*GT;
  int b  = blockIdx.z;
  int tid = threadIdx.x;
  int tm = tid&15, tn = tid>>4;
  float acc[4][4];
  #pragma unroll
  for(int i=0;i<4;i++)
    #pragma unroll
    for(int j=0;j<4;j++) acc[i][j]=0.f;
  for(int k0=0;k0<EDIM;k0+=KT){
    {
      int mloc = tid>>2;
      int kloc = (tid&3)*4;
      const float4 av = *(const float4*)&z[((size_t)b*TSEQ + m0+mloc)*EDIM + k0 + kloc];
      As[kloc+0][mloc]=av.x; As[kloc+1][mloc]=av.y; As[kloc+2][mloc]=av.z; As[kloc+3][mloc]=av.w;
    }
    {
      int nloc = tid>>2;
      int kloc = (tid&3)*4;
      const float4 bv = *(const float4*)&z[((size_t)(b+NB)*TSEQ + n0+nloc)*EDIM + k0 + kloc];
      Bs[kloc+0][nloc]=bv.x; Bs[kloc+1][nloc]=bv.y; Bs[kloc+2][nloc]=bv.z; Bs[kloc+3][nloc]=bv.w;
    }
    __syncthreads();
    #pragma unroll
    for(int kk=0;kk<KT;kk++){
      float4 av = *(const float4*)&As[kk][tm*4];
      float4 bv = *(const float4*)&Bs[kk][tn*4];
      float a[4] = {av.x,av.y,av.z,av.w};
      float b2[4] = {bv.x,bv.y,bv.z,bv.w};
      #pragma unroll
      for(int i=0;i<4;i++)
        #pragma unroll
        for(int j=0;j<4;j++) acc[i][j] = fmaf(a[i], b2[j], acc[i][j]);
    }
    __syncthreads();
  }
  #pragma unroll
  for(int i=0;i<4;i++){
    int m = m0 + tm*4 + i;
    #pragma unroll
    for(int j=0;j<4;j++){
      int n = n0 + tn*4 + j;
      theta[((size_t)b*TSEQ + m)*TSEQ + n] = acc[i][j];
    }
  }
}

__global__ __launch_bounds__(256) void mean_k(const float* __restrict__ z, float* __restrict__ zmean){
  int r = blockIdx.x;
  int tid = threadIdx.x;
  for(int ee=tid; ee<EDIM; ee+=256){
    float acc=0.f;
    for(int t=0;t<TSEQ;t++) acc += z[((size_t)r*TSEQ+t)*EDIM+ee];
    zmean[(size_t)r*EDIM+ee] = acc*(1.0f/TSEQ);
  }
}

__global__ __launch_bounds__(256) void gap_k(const float* __restrict__ zmean,
        const float* __restrict__ W_gap, const float* __restrict__ b_gap, float* __restrict__ Aout){
  __shared__ float red[256];
  int b = blockIdx.x;
  int tid = threadIdx.x;
  float acc=0.f;
  for(int i=tid;i<2*EDIM;i+=256){
    float m = (i<EDIM)? zmean[(size_t)b*EDIM+i] : zmean[(size_t)(b+NB)*EDIM + (i-EDIM)];
    acc = fmaf(m, W_gap[i], acc);
  }
  red[tid]=acc; __syncthreads();
  for(int s=128;s>0;s>>=1){ if(tid<s) red[tid]+=red[tid+s]; __syncthreads(); }
  if(tid==0) Aout[b] = red[0] + b_gap[0];
}

// Needleman-Wunsch: one wave per batch; 8 DP cells per lane in registers.
__global__ __launch_bounds__(64) void nw_k(const float* __restrict__ theta,
        const float* __restrict__ Aout, float* __restrict__ out){
  const float L2E = 1.4426950408889634f, LN2 = 0.6931471805599453f;
  int b = blockIdx.x;
  int lane = threadIdx.x;
  float A = Aout[b];
  float p1[8], p2[8];
  #pragma unroll
  for(int i=0;i<8;i++){ p1[i]=NEGV; p2[i]=NEGV; }
  float p1_0 = NEGV, p2_0 = 0.0f;
  const float* th = theta + (size_t)b*TSEQ*TSEQ;
  for(int k=2;k<=1024;k++){
    float pm1 = __shfl_up(p1[7],1);
    float pm2 = __shfl_up(p2[7],1);
    if(lane==0){ pm1 = p1_0; pm2 = p2_0; }
    float td[8];
    #pragma unroll
    for(int cx=0;cx<8;cx++){
      int i = lane*8+1+cx;
      int j = k-i;
      int jc = j<1?1:(j>512?512:j);
      td[cx] = th[(size_t)(i-1)*TSEQ + (jc-1)];
    }
    float cur[8];
    #pragma unroll
    for(int cx=0;cx<8;cx++){
      int i = lane*8+1+cx;
      int j = k-i;
      bool valid = (j>=1)&&(j<=512);
      float a  = (cx==0? pm1 : p1[cx-1]) + A;
      float bb = (cx==0? pm2 : p2[cx-1]);
      float cc = p1[cx] + A;
      float m = fmaxf(fmaxf(a,bb),cc);
      float sum = exp2f((a-m)*L2E) + exp2f((bb-m)*L2E) + exp2f((cc-m)*L2E);
      float v = m + log2f(sum)*LN2;
      cur[cx] = valid ? td[cx] + v : NEGV;
    }
    #pragma unroll
    for(int cx=0;cx<8;cx++){ p2[cx]=p1[cx]; p1[cx]=cur[cx]; }
    p2_0 = p1_0; p1_0 = NEGV;
  }
  if(lane==63) out[b] = p1[7];
}

extern "C" void kernel_launch(void* const* d_in, const int* in_sizes, int n_in,
                              void* d_out, int out_size, void* d_ws, size_t ws_size,
                              hipStream_t stream) {
  (void)in_sizes; (void)n_in; (void)out_size; (void)ws_size;
  const int*   x      = (const int*)d_in[0];
  const int*   y      = (const int*)d_in[1];
  const float* emb    = (const float*)d_in[2];
  const float* W_ih   = (const float*)d_in[3];
  const float* W_hh   = (const float*)d_in[4];
  const float* b_lstm = (const float*)d_in[5];
  const float* W_out  = (const float*)d_in[6];
  const float* b_out  = (const float*)d_in[7];
  const float* W_gap  = (const float*)d_in[8];
  const float* b_gap  = (const float*)d_in[9];
  float* out = (float*)d_out;

  char* ws = (char*)d_ws;
  const size_t OFF_TABLE = 0;                        // 180224
  const size_t OFF_WSWZ  = 184320;                   // 2MB bf16 swizzled W_hh
  const size_t OFF_HSWZ  = OFF_WSWZ + 2097152;       // 2 x 64KB bf16 swizzled h
  const size_t OFF_FLAGS = OFF_HSWZ + 131072;        // 32 flags x 128B = 4KB
  const size_t OFF_HS    = OFF_FLAGS + 4096;         // 64MB
  const size_t OFF_Z     = OFF_HS + 67108864;        // 64MB
  const size_t OFF_THETA = OFF_Z + 67108864;         // 32MB
  const size_t OFF_ZMEAN = OFF_THETA + 33554432;     // 128KB
  const size_t OFF_AOUT  = OFF_ZMEAN + 131072;       // 128B
  float* table = (float*)(ws + OFF_TABLE);
  unsigned short* Wswz = (unsigned short*)(ws + OFF_WSWZ);
  unsigned short* hswz = (unsigned short*)(ws + OFF_HSWZ);
  unsigned* flags = (unsigned*)(ws + OFF_FLAGS);
  float* hs    = (float*)(ws + OFF_HS);
  float* z     = (float*)(ws + OFF_Z);
  float* theta = (float*)(ws + OFF_THETA);
  float* zmean = (float*)(ws + OFF_ZMEAN);
  float* Aout  = (float*)(ws + OFF_AOUT);

  hipMemsetAsync(hswz,  0, 65536, stream);           // h(0) = 0 (buffer 0)
  hipMemsetAsync(flags, 0, 4096,  stream);           // flags = 0 every launch

  table_k<<<dim3(8,22), 256, 0, stream>>>(emb, W_ih, b_lstm, table);
  wprep_k<<<2048, 64, 0, stream>>>(W_hh, Wswz);
  lstm_persist<<<NWG, 512, 0, stream>>>(x, y, table, Wswz, hswz, hs, flags);
  zproj_k<<<dim3(512,8), 256, 0, stream>>>(hs, W_out, b_out, z);
  theta_k<<<dim3(8,8,32), 256, 0, stream>>>(z, theta);
  mean_k<<<64, 256, 0, stream>>>(z, zmean);
  gap_k<<<32, 256, 0, stream>>>(zmean, W_gap, b_gap, Aout);
  nw_k<<<32, 64, 0, stream>>>(theta, Aout, out);
}

// Round 6
// 3113.944 us; speedup vs baseline: 1.6514x; 1.0318x over previous
//
#include <hip/hip_runtime.h>
#include <math.h>

#define TSEQ 512
#define HDIM 512
#define EDIM 512
#define NB   32
#define ROWS 64
#define GATES 2048
#define NEGV -1000000000.0f

typedef __attribute__((ext_vector_type(8))) short bf16x8;
typedef __attribute__((ext_vector_type(4))) float f32x4;

__device__ __forceinline__ float sigf(float x){ return 1.0f/(1.0f + __expf(-x)); }

__device__ __forceinline__ float tanhfast(float x){
  float t = __expf(-2.0f*fabsf(x));
  float r = (1.0f - t)/(1.0f + t);
  return copysignf(r, x);
}

__device__ __forceinline__ unsigned short f2bf(float f){
  unsigned int u = __builtin_bit_cast(unsigned int, f);
  unsigned int r = (u + 0x7fff + ((u>>16)&1)) >> 16;
  return (unsigned short)r;
}

// table[v][j] = sum_k emb[v][k] * W_ih[k][j] + b_lstm[j]   (fp32)
__global__ __launch_bounds__(256) void table_k(const float* __restrict__ emb,
        const float* __restrict__ W_ih, const float* __restrict__ b_lstm,
        float* __restrict__ table){
  int j = blockIdx.x*256 + threadIdx.x;
  int v = blockIdx.y;
  float acc = b_lstm[j];
  #pragma unroll 4
  for(int k=0;k<EDIM;k++) acc = fmaf(emb[v*EDIM+k], W_ih[(size_t)k*GATES+j], acc);
  table[(size_t)v*GATES+j] = acc;
}

// W_hh -> bf16 B-fragment order. cid = js*64 + g*16 + kc.
__global__ __launch_bounds__(64) void wprep_k(const float* __restrict__ W_hh,
        unsigned short* __restrict__ Wswz){
  int cid = blockIdx.x;           // 0..2047
  int lane = threadIdx.x;
  int js = cid>>6, g = (cid>>4)&3, kc = cid&15;
  int col = g*512 + js*16 + (lane&15);
  int kbase = kc*32 + (lane>>4)*8;
  unsigned short v[8];
  #pragma unroll
  for(int e=0;e<8;e++) v[e] = f2bf(W_hh[(size_t)(kbase+e)*GATES + col]);
  *(uint4*)&Wswz[((size_t)cid*64 + lane)*8] = *(const uint4*)v;
}

// W_out -> bf16 B-fragment order. cid = nc*16 + kc.
__global__ __launch_bounds__(64) void wprep2_k(const float* __restrict__ W_out,
        unsigned short* __restrict__ wsw){
  int cid = blockIdx.x;           // 0..511
  int lane = threadIdx.x;
  int nc = cid>>4, kc = cid&15;
  int col = nc*16 + (lane&15);
  int kb = kc*32 + (lane>>4)*8;
  unsigned short v[8];
  #pragma unroll
  for(int e=0;e<8;e++) v[e] = f2bf(W_out[(size_t)(kb+e)*EDIM + col]);
  *(uint4*)&wsw[((size_t)cid*64 + lane)*8] = *(const uint4*)v;
}

// Persistent LSTM: 128 single-wave WGs. wave = (chain c, row-half mh, j-slice js).
// All 4 gates per wave -> in-register gate combine, zero intra-WG syncs.
__global__ __launch_bounds__(64,1) void lstm_wave(const int* __restrict__ x, const int* __restrict__ y,
        const float* __restrict__ table, const unsigned short* __restrict__ Wswz,
        unsigned short* __restrict__ hxchg, unsigned short* __restrict__ hsb,
        unsigned* __restrict__ flags){
  __shared__ unsigned short wlds[32768];   // 64KB: [g][kc][lane][8]
  int w = blockIdx.x;
  int c = w>>6, mh = (w>>5)&1, js = w&31;
  int lane = threadIdx.x;

  { // stage W slice for js (contiguous 64KB)
    const uint4* src = (const uint4*)(Wswz + (size_t)js*32768);
    uint4* dst = (uint4*)wlds;
    for(int i=0;i<64;i++) dst[lane + i*64] = src[lane + i*64];
  }
  __syncthreads();

  unsigned* fp = flags + (c*2+mh)*32;
  const int* tokbase = c ? y : x;
  int jloc = lane&15;
  int j    = js*16 + jloc;
  int hi   = (j>>3)&3;
  int kc_o = j>>5;
  int e_o  = j&7;
  int rl0  = (lane>>4)*4;
  unsigned pub_vo = (unsigned)(((kc_o*64 + (rl0 | (hi<<4)))*8 + e_o)*2);
  int rbase = c*32 + mh*16 + rl0;       // global row of q=0
  float cst0=0.f,cst1=0.f,cst2=0.f,cst3=0.f;

  unsigned short* hb0 = hxchg + (size_t)(c*2+mh)*2*8192;   // [buf][8192] elems

  for(int s=0;s<TSEQ;s++){
    if(s>0){
      unsigned fv = (lane<32)? __hip_atomic_load(fp+lane, __ATOMIC_RELAXED, __HIP_MEMORY_SCOPE_AGENT) : 0xFFFFFFFFu;
      while(!__all((int)(fv >= (unsigned)s))){
        fv = (lane<32)? __hip_atomic_load(fp+lane, __ATOMIC_RELAXED, __HIP_MEMORY_SCOPE_AGENT) : 0xFFFFFFFFu;
      }
    }
    const unsigned short* hin = hb0 + (size_t)(s&1)*8192;
    uint4 f0,f1,f2,f3,f4,f5,f6,f7,f8,f9,f10,f11,f12,f13,f14,f15;
    unsigned a0v = (unsigned)lane*16u, a1v = a0v+4096u, a2v = a0v+8192u, a3v = a0v+12288u;
    asm volatile(
      "global_load_dwordx4 %[f0], %[a0], %[sb] sc0 sc1\n\t"
      "global_load_dwordx4 %[f1], %[a0], %[sb] offset:1024 sc0 sc1\n\t"
      "global_load_dwordx4 %[f2], %[a0], %[sb] offset:2048 sc0 sc1\n\t"
      "global_load_dwordx4 %[f3], %[a0], %[sb] offset:3072 sc0 sc1\n\t"
      "global_load_dwordx4 %[f4], %[a1], %[sb] sc0 sc1\n\t"
      "global_load_dwordx4 %[f5], %[a1], %[sb] offset:1024 sc0 sc1\n\t"
      "global_load_dwordx4 %[f6], %[a1], %[sb] offset:2048 sc0 sc1\n\t"
      "global_load_dwordx4 %[f7], %[a1], %[sb] offset:3072 sc0 sc1\n\t"
      "global_load_dwordx4 %[f8], %[a2], %[sb] sc0 sc1\n\t"
      "global_load_dwordx4 %[f9], %[a2], %[sb] offset:1024 sc0 sc1\n\t"
      "global_load_dwordx4 %[f10], %[a2], %[sb] offset:2048 sc0 sc1\n\t"
      "global_load_dwordx4 %[f11], %[a2], %[sb] offset:3072 sc0 sc1\n\t"
      "global_load_dwordx4 %[f12], %[a3], %[sb] sc0 sc1\n\t"
      "global_load_dwordx4 %[f13], %[a3], %[sb] offset:1024 sc0 sc1\n\t"
      "global_load_dwordx4 %[f14], %[a3], %[sb] offset:2048 sc0 sc1\n\t"
      "global_load_dwordx4 %[f15], %[a3], %[sb] offset:3072 sc0 sc1\n\t"
      "s_waitcnt vmcnt(0)"
      : [f0]"=&v"(f0),[f1]"=&v"(f1),[f2]"=&v"(f2),[f3]"=&v"(f3),
        [f4]"=&v"(f4),[f5]"=&v"(f5),[f6]"=&v"(f6),[f7]"=&v"(f7),
        [f8]"=&v"(f8),[f9]"=&v"(f9),[f10]"=&v"(f10),[f11]"=&v"(f11),
        [f12]"=&v"(f12),[f13]"=&v"(f13),[f14]"=&v"(f14),[f15]"=&v"(f15)
      : [a0]"v"(a0v),[a1]"v"(a1v),[a2]"v"(a2v),[a3]"v"(a3v),
        [sb]"s"((const void*)hin)
      : "memory");
    bf16x8 af[16];
    af[0]=__builtin_bit_cast(bf16x8,f0);   af[1]=__builtin_bit_cast(bf16x8,f1);
    af[2]=__builtin_bit_cast(bf16x8,f2);   af[3]=__builtin_bit_cast(bf16x8,f3);
    af[4]=__builtin_bit_cast(bf16x8,f4);   af[5]=__builtin_bit_cast(bf16x8,f5);
    af[6]=__builtin_bit_cast(bf16x8,f6);   af[7]=__builtin_bit_cast(bf16x8,f7);
    af[8]=__builtin_bit_cast(bf16x8,f8);   af[9]=__builtin_bit_cast(bf16x8,f9);
    af[10]=__builtin_bit_cast(bf16x8,f10); af[11]=__builtin_bit_cast(bf16x8,f11);
    af[12]=__builtin_bit_cast(bf16x8,f12); af[13]=__builtin_bit_cast(bf16x8,f13);
    af[14]=__builtin_bit_cast(bf16x8,f14); af[15]=__builtin_bit_cast(bf16x8,f15);

    f32x4 acc0={0,0,0,0}, acc1={0,0,0,0}, acc2={0,0,0,0}, acc3={0,0,0,0};
    #pragma unroll
    for(int kc=0;kc<16;kc++){
      bf16x8 w0 = *(const bf16x8*)(const void*)&wlds[((0*16+kc)*64 + lane)*8];
      bf16x8 w1 = *(const bf16x8*)(const void*)&wlds[((1*16+kc)*64 + lane)*8];
      bf16x8 w2 = *(const bf16x8*)(const void*)&wlds[((2*16+kc)*64 + lane)*8];
      bf16x8 w3 = *(const bf16x8*)(const void*)&wlds[((3*16+kc)*64 + lane)*8];
      acc0 = __builtin_amdgcn_mfma_f32_16x16x32_bf16(af[kc], w0, acc0, 0,0,0);
      acc1 = __builtin_amdgcn_mfma_f32_16x16x32_bf16(af[kc], w1, acc1, 0,0,0);
      acc2 = __builtin_amdgcn_mfma_f32_16x16x32_bf16(af[kc], w2, acc2, 0,0,0);
      acc3 = __builtin_amdgcn_mfma_f32_16x16x32_bf16(af[kc], w3, acc3, 0,0,0);
    }

    unsigned short* hout = hb0 + (size_t)((s+1)&1)*8192;
    unsigned hv[4];
    int sc = s>>4, sl = s&15;
    #pragma unroll
    for(int q=0;q<4;q++){
      int tok = tokbase[(mh*16 + rl0 + q)*TSEQ + s];
      const float* tbl = table + (size_t)tok*GATES;
      float zi = acc0[q] + tbl[j];
      float zf = acc1[q] + tbl[512+j];
      float zg = acc2[q] + tbl[1024+j];
      float zo = acc3[q] + tbl[1536+j];
      float cold = (q==0)?cst0:((q==1)?cst1:((q==2)?cst2:cst3));
      float cn = sigf(zf)*cold + sigf(zi)*tanhfast(zg);
      float h  = sigf(zo)*tanhfast(cn);
      if(q==0)cst0=cn; else if(q==1)cst1=cn; else if(q==2)cst2=cn; else cst3=cn;
      hv[q] = (unsigned)f2bf(h);
      int r = rbase + q;
      int mc = r*32 + sc;
      hsb[((size_t)(mc*16 + kc_o)*64 + (sl|(hi<<4)))*8 + e_o] = (unsigned short)hv[q];
    }
    asm volatile(
      "global_store_short %[a], %[d0], %[sb] sc0 sc1\n\t"
      "global_store_short %[a], %[d1], %[sb] offset:16 sc0 sc1\n\t"
      "global_store_short %[a], %[d2], %[sb] offset:32 sc0 sc1\n\t"
      "global_store_short %[a], %[d3], %[sb] offset:48 sc0 sc1\n\t"
      "s_waitcnt vmcnt(0)"
      :: [a]"v"(pub_vo), [d0]"v"(hv[0]),[d1]"v"(hv[1]),[d2]"v"(hv[2]),[d3]"v"(hv[3]),
         [sb]"s"((void*)hout)
      : "memory");
    if(lane==0)
      __hip_atomic_store(fp+js, (unsigned)(s+1), __ATOMIC_RELAXED, __HIP_MEMORY_SCOPE_AGENT);
  }
}

// z = hsb @ W_out + b_out  (bf16 MFMA). Writes z fp32 + bf16 frags for theta.
__global__ __launch_bounds__(256) void zproj_mfma(const unsigned short* __restrict__ hsb,
        const unsigned short* __restrict__ woutswz, const float* __restrict__ b_out,
        float* __restrict__ z, unsigned short* __restrict__ zxA, unsigned short* __restrict__ zyB){
  int tid = threadIdx.x, wv = tid>>6, lane = tid&63;
  int m0 = blockIdx.x*128 + (wv>>1)*64;
  int n0 = blockIdx.y*128 + (wv&1)*64;
  int mc0 = m0>>4, nc0 = n0>>4;
  const uint4* ha = (const uint4*)hsb;
  const uint4* wb = (const uint4*)woutswz;
  f32x4 acc[4][4];
  #pragma unroll
  for(int i=0;i<4;i++)
    #pragma unroll
    for(int k2=0;k2<4;k2++) acc[i][k2] = (f32x4){0,0,0,0};
  for(int kc=0;kc<16;kc++){
    bf16x8 a[4], b[4];
    #pragma unroll
    for(int i=0;i<4;i++){
      a[i] = __builtin_bit_cast(bf16x8, ha[((size_t)((mc0+i)*16 + kc))*64 + lane]);
      b[i] = __builtin_bit_cast(bf16x8, wb[((size_t)((nc0+i)*16 + kc))*64 + lane]);
    }
    #pragma unroll
    for(int mi=0;mi<4;mi++)
      #pragma unroll
      for(int ci=0;ci<4;ci++)
        acc[mi][ci] = __builtin_amdgcn_mfma_f32_16x16x32_bf16(a[mi], b[ci], acc[mi][ci], 0,0,0);
  }
  int r = m0>>9;
  bool isx = (r < NB);
  unsigned short* zb = isx ? zxA : zyB;
  int bb = isx ? r : r-NB;
  #pragma unroll
  for(int ci=0;ci<4;ci++){
    int n = n0 + ci*16 + (lane&15);
    float bo = b_out[n];
    int kcz = n>>5, hi = (n>>3)&3, ez = n&7;
    #pragma unroll
    for(int mi=0;mi<4;mi++){
      #pragma unroll
      for(int q=0;q<4;q++){
        int m = m0 + mi*16 + (lane>>4)*4 + q;
        float zv = acc[mi][ci][q] + bo;
        z[(size_t)m*EDIM + n] = zv;
        int i = m&511;
        zb[(((size_t)(bb*32 + (i>>4))*16 + kcz)*64 + ((i&15)|(hi<<4)))*8 + ez] = f2bf(zv);
      }
    }
  }
}

// theta[b] = zx[b] @ zy[b]^T   (bf16 MFMA from prebuilt frags)
__global__ __launch_bounds__(256) void theta_mfma(const unsigned short* __restrict__ zxA,
        const unsigned short* __restrict__ zyB, float* __restrict__ theta){
  int tid = threadIdx.x, wv = tid>>6, lane = tid&63;
  int b = blockIdx.z;
  int i0 = blockIdx.x*128 + (wv>>1)*64;
  int j0 = blockIdx.y*128 + (wv&1)*64;
  int ic0 = i0>>4, jc0 = j0>>4;
  const uint4* pa = (const uint4*)zxA;
  const uint4* pb = (const uint4*)zyB;
  f32x4 acc[4][4];
  #pragma unroll
  for(int i=0;i<4;i++)
    #pragma unroll
    for(int k2=0;k2<4;k2++) acc[i][k2] = (f32x4){0,0,0,0};
  for(int kc=0;kc<16;kc++){
    bf16x8 a[4], bfr[4];
    #pragma unroll
    for(int i=0;i<4;i++){
      a[i]   = __builtin_bit_cast(bf16x8, pa[((size_t)(b*32 + ic0+i)*16 + kc)*64 + lane]);
      bfr[i] = __builtin_bit_cast(bf16x8, pb[((size_t)(b*32 + jc0+i)*16 + kc)*64 + lane]);
    }
    #pragma unroll
    for(int mi=0;mi<4;mi++)
      #pragma unroll
      for(int ci=0;ci<4;ci++)
        acc[mi][ci] = __builtin_amdgcn_mfma_f32_16x16x32_bf16(a[mi], bfr[ci], acc[mi][ci], 0,0,0);
  }
  #pragma unroll
  for(int mi=0;mi<4;mi++){
    #pragma unroll
    for(int ci=0;ci<4;ci++){
      #pragma unroll
      for(int q=0;q<4;q++){
        int i = i0 + mi*16 + (lane>>4)*4 + q;
        int jj = j0 + ci*16 + (lane&15);
        theta[((size_t)b*TSEQ + i)*TSEQ + jj] = acc[mi][ci][q];
      }
    }
  }
}

__global__ __launch_bounds__(256) void mean_k(const float* __restrict__ z, float* __restrict__ zmean){
  int r = blockIdx.x;
  int tid = threadIdx.x;
  for(int ee=tid; ee<EDIM; ee+=256){
    float acc=0.f;
    for(int t=0;t<TSEQ;t++) acc += z[((size_t)r*TSEQ+t)*EDIM+ee];
    zmean[(size_t)r*EDIM+ee] = acc*(1.0f/TSEQ);
  }
}

__global__ __launch_bounds__(256) void gap_k(const float* __restrict__ zmean,
        const float* __restrict__ W_gap, const float* __restrict__ b_gap, float* __restrict__ Aout){
  __shared__ float red[256];
  int b = blockIdx.x;
  int tid = threadIdx.x;
  float acc=0.f;
  for(int i=tid;i<2*EDIM;i+=256){
    float m = (i<EDIM)? zmean[(size_t)b*EDIM+i] : zmean[(size_t)(b+NB)*EDIM + (i-EDIM)];
    acc = fmaf(m, W_gap[i], acc);
  }
  red[tid]=acc; __syncthreads();
  for(int s=128;s>0;s>>=1){ if(tid<s) red[tid]+=red[tid+s]; __syncthreads(); }
  if(tid==0) Aout[b] = red[0] + b_gap[0];
}

// Needleman-Wunsch: one wave per batch; 8 DP cells per lane in registers.
__global__ __launch_bounds__(64) void nw_k(const float* __restrict__ theta,
        const float* __restrict__ Aout, float* __restrict__ out){
  const float L2E = 1.4426950408889634f, LN2 = 0.6931471805599453f;
  int b = blockIdx.x;
  int lane = threadIdx.x;
  float A = Aout[b];
  float p1[8], p2[8];
  #pragma unroll
  for(int i=0;i<8;i++){ p1[i]=NEGV; p2[i]=NEGV; }
  float p1_0 = NEGV, p2_0 = 0.0f;
  const float* th = theta + (size_t)b*TSEQ*TSEQ;
  for(int k=2;k<=1024;k++){
    float pm1 = __shfl_up(p1[7],1);
    float pm2 = __shfl_up(p2[7],1);
    if(lane==0){ pm1 = p1_0; pm2 = p2_0; }
    float td[8];
    #pragma unroll
    for(int cx=0;cx<8;cx++){
      int i = lane*8+1+cx;
      int jq = k-i;
      int jc = jq<1?1:(jq>512?512:jq);
      td[cx] = th[(size_t)(i-1)*TSEQ + (jc-1)];
    }
    float cur[8];
    #pragma unroll
    for(int cx=0;cx<8;cx++){
      int i = lane*8+1+cx;
      int jq = k-i;
      bool valid = (jq>=1)&&(jq<=512);
      float a  = (cx==0? pm1 : p1[cx-1]) + A;
      float bb = (cx==0? pm2 : p2[cx-1]);
      float cc = p1[cx] + A;
      float m = fmaxf(fmaxf(a,bb),cc);
      float sum = exp2f((a-m)*L2E) + exp2f((bb-m)*L2E) + exp2f((cc-m)*L2E);
      float v = m + log2f(sum)*LN2;
      cur[cx] = valid ? td[cx] + v : NEGV;
    }
    #pragma unroll
    for(int cx=0;cx<8;cx++){ p2[cx]=p1[cx]; p1[cx]=cur[cx]; }
    p2_0 = p1_0; p1_0 = NEGV;
  }
  if(lane==63) out[b] = p1[7];
}

extern "C" void kernel_launch(void* const* d_in, const int* in_sizes, int n_in,
                              void* d_out, int out_size, void* d_ws, size_t ws_size,
                              hipStream_t stream) {
  (void)in_sizes; (void)n_in; (void)out_size; (void)ws_size;
  const int*   x      = (const int*)d_in[0];
  const int*   y      = (const int*)d_in[1];
  const float* emb    = (const float*)d_in[2];
  const float* W_ih   = (const float*)d_in[3];
  const float* W_hh   = (const float*)d_in[4];
  const float* b_lstm = (const float*)d_in[5];
  const float* W_out  = (const float*)d_in[6];
  const float* b_out  = (const float*)d_in[7];
  const float* W_gap  = (const float*)d_in[8];
  const float* b_gap  = (const float*)d_in[9];
  float* out = (float*)d_out;

  char* ws = (char*)d_ws;
  const size_t OFF_TABLE = 0;                         // 180224 (pad 184320)
  const size_t OFF_WSWZ  = 184320;                    // 2MB
  const size_t OFF_WOUT  = OFF_WSWZ  + 2097152;       // 512KB
  const size_t OFF_HXCHG = OFF_WOUT  + 524288;        // 128KB
  const size_t OFF_FLAGS = OFF_HXCHG + 131072;        // 4KB (512B used)
  const size_t OFF_HSB   = OFF_FLAGS + 4096;          // 32MB
  const size_t OFF_Z     = OFF_HSB   + 33554432;      // 64MB
  const size_t OFF_ZXA   = OFF_Z     + 67108864;      // 16MB
  const size_t OFF_ZYB   = OFF_ZXA   + 16777216;      // 16MB
  const size_t OFF_THETA = OFF_ZYB   + 16777216;      // 32MB
  const size_t OFF_ZMEAN = OFF_THETA + 33554432;      // 128KB
  const size_t OFF_AOUT  = OFF_ZMEAN + 131072;        // 128B
  float* table = (float*)(ws + OFF_TABLE);
  unsigned short* Wswz    = (unsigned short*)(ws + OFF_WSWZ);
  unsigned short* woutswz = (unsigned short*)(ws + OFF_WOUT);
  unsigned short* hxchg   = (unsigned short*)(ws + OFF_HXCHG);
  unsigned* flags = (unsigned*)(ws + OFF_FLAGS);
  unsigned short* hsb = (unsigned short*)(ws + OFF_HSB);
  float* z     = (float*)(ws + OFF_Z);
  unsigned short* zxA = (unsigned short*)(ws + OFF_ZXA);
  unsigned short* zyB = (unsigned short*)(ws + OFF_ZYB);
  float* theta = (float*)(ws + OFF_THETA);
  float* zmean = (float*)(ws + OFF_ZMEAN);
  float* Aout  = (float*)(ws + OFF_AOUT);

  hipMemsetAsync(hxchg, 0, 131072, stream);   // h(0) = 0, both buffers
  hipMemsetAsync(flags, 0, 4096,  stream);    // flags = 0 each launch

  table_k<<<dim3(8,22), 256, 0, stream>>>(emb, W_ih, b_lstm, table);
  wprep_k<<<2048, 64, 0, stream>>>(W_hh, Wswz);
  wprep2_k<<<512, 64, 0, stream>>>(W_out, woutswz);
  lstm_wave<<<128, 64, 0, stream>>>(x, y, table, Wswz, hxchg, hsb, flags);
  zproj_mfma<<<dim3(256,4), 256, 0, stream>>>(hsb, woutswz, b_out, z, zxA, zyB);
  theta_mfma<<<dim3(4,4,32), 256, 0, stream>>>(zxA, zyB, theta);
  mean_k<<<64, 256, 0, stream>>>(z, zmean);
  gap_k<<<32, 256, 0, stream>>>(zmean, W_gap, b_gap, Aout);
  nw_k<<<32, 64, 0, stream>>>(theta, Aout, out);
}

// Round 7
// 3013.111 us; speedup vs baseline: 1.7067x; 1.0335x over previous
//
#include <hip/hip_runtime.h>
#include <math.h>

#define TSEQ 512
#define HDIM 512
#define EDIM 512
#define NB   32
#define ROWS 64
#define GATES 2048
#define NEGV -1000000000.0f

typedef __attribute__((ext_vector_type(8))) short bf16x8;
typedef __attribute__((ext_vector_type(4))) float f32x4;

__device__ __forceinline__ float sigf(float x){ return 1.0f/(1.0f + __expf(-x)); }

__device__ __forceinline__ float tanhfast(float x){
  float t = __expf(-2.0f*fabsf(x));
  float r = (1.0f - t)/(1.0f + t);
  return copysignf(r, x);
}

__device__ __forceinline__ unsigned short f2bf(float f){
  unsigned int u = __builtin_bit_cast(unsigned int, f);
  unsigned int r = (u + 0x7fff + ((u>>16)&1)) >> 16;
  return (unsigned short)r;
}

// table[v][j] = sum_k emb[v][k] * W_ih[k][j] + b_lstm[j]   (fp32)
__global__ __launch_bounds__(256) void table_k(const float* __restrict__ emb,
        const float* __restrict__ W_ih, const float* __restrict__ b_lstm,
        float* __restrict__ table){
  int j = blockIdx.x*256 + threadIdx.x;
  int v = blockIdx.y;
  float acc = b_lstm[j];
  #pragma unroll 4
  for(int k=0;k<EDIM;k++) acc = fmaf(emb[v*EDIM+k], W_ih[(size_t)k*GATES+j], acc);
  table[(size_t)v*GATES+j] = acc;
}

// W_hh -> bf16 B-fragment order. cid = js*64 + g*16 + kc.
__global__ __launch_bounds__(64) void wprep_k(const float* __restrict__ W_hh,
        unsigned short* __restrict__ Wswz){
  int cid = blockIdx.x;           // 0..2047
  int lane = threadIdx.x;
  int js = cid>>6, g = (cid>>4)&3, kc = cid&15;
  int col = g*512 + js*16 + (lane&15);
  int kbase = kc*32 + (lane>>4)*8;
  unsigned short v[8];
  #pragma unroll
  for(int e=0;e<8;e++) v[e] = f2bf(W_hh[(size_t)(kbase+e)*GATES + col]);
  *(uint4*)&Wswz[((size_t)cid*64 + lane)*8] = *(const uint4*)v;
}

// W_out -> bf16 B-fragment order. cid = nc*16 + kc.
__global__ __launch_bounds__(64) void wprep2_k(const float* __restrict__ W_out,
        unsigned short* __restrict__ wsw){
  int cid = blockIdx.x;           // 0..511
  int lane = threadIdx.x;
  int nc = cid>>4, kc = cid&15;
  int col = nc*16 + (lane&15);
  int kb = kc*32 + (lane>>4)*8;
  unsigned short v[8];
  #pragma unroll
  for(int e=0;e<8;e++) v[e] = f2bf(W_out[(size_t)(kb+e)*EDIM + col]);
  *(uint4*)&wsw[((size_t)cid*64 + lane)*8] = *(const uint4*)v;
}

// Persistent LSTM, tagged-data exchange: 128 single-wave WGs.
// Each h value published as dword (bf16<<16)|step_tag; consumers poll by
// reloading fragments until all tags match. One L3 round trip per step.
__global__ __launch_bounds__(64,1) void lstm_wave(const int* __restrict__ x, const int* __restrict__ y,
        const float* __restrict__ table, const unsigned short* __restrict__ Wswz,
        unsigned* __restrict__ hx, unsigned short* __restrict__ hsb){
  __shared__ unsigned short wlds[32768];   // 64KB: [g][kc][lane][8]
  int w = blockIdx.x;
  int c = w>>6, mh = (w>>5)&1, js = w&31;
  int gid = w>>5;                          // group 0..3 = (c,mh)
  int lane = threadIdx.x;

  { // stage W slice for js (contiguous 64KB)
    const uint4* src = (const uint4*)(Wswz + (size_t)js*32768);
    uint4* dst = (uint4*)wlds;
    #pragma unroll
    for(int i=0;i<64;i++) dst[lane + i*64] = src[lane + i*64];
  }
  __syncthreads();

  const int* tokbase = c ? y : x;
  int jloc = lane&15;
  int j    = js*16 + jloc;
  int hi   = (j>>3)&3;
  int kc_o = j>>5;
  int e_o  = j&7;
  int rl0  = (lane>>4)*4;
  unsigned pub_vo = (unsigned)(((kc_o*64 + (rl0|(hi<<4)))*8 + e_o)*4);
  int rbase = c*32 + mh*16 + rl0;
  float cst[4] = {0.f,0.f,0.f,0.f};

  unsigned* gbase = hx + (size_t)gid*16384;   // 2 parity buffers x 8192 dwords
  unsigned vo32 = (unsigned)lane*32u;

  for(int s=0;s<TSEQ;s++){
    const unsigned* hin = gbase + (size_t)(s&1)*8192;
    unsigned* hout      = gbase + (size_t)((s+1)&1)*8192;
    unsigned tagexp = (unsigned)s;

    uint4 ra[32];
    while(true){
      #pragma unroll
      for(int kc=0;kc<16;kc++){
        asm volatile(
          "global_load_dwordx4 %0, %2, %3 sc0 sc1\n\t"
          "global_load_dwordx4 %1, %2, %3 offset:16 sc0 sc1"
          : "=&v"(ra[2*kc]), "=&v"(ra[2*kc+1])
          : "v"(vo32), "s"((const void*)(hin + (size_t)kc*512))
          : "memory");
      }
      asm volatile("s_waitcnt vmcnt(0)" ::: "memory");
      __builtin_amdgcn_sched_barrier(0);     // rule-18 fence: no use before waitcnt
      unsigned acc = 0u;
      #pragma unroll
      for(int i=0;i<32;i++)
        acc |= (ra[i].x ^ tagexp) | (ra[i].y ^ tagexp) | (ra[i].z ^ tagexp) | (ra[i].w ^ tagexp);
      if(__all((int)((acc & 0xFFFFu) == 0u))) break;
    }

    // unpack high16s -> bf16 A-fragments
    bf16x8 af[16];
    #pragma unroll
    for(int kc=0;kc<16;kc++){
      uint4 pk_;
      pk_.x = (ra[2*kc].x  >>16) | (ra[2*kc].y  & 0xFFFF0000u);
      pk_.y = (ra[2*kc].z  >>16) | (ra[2*kc].w  & 0xFFFF0000u);
      pk_.z = (ra[2*kc+1].x>>16) | (ra[2*kc+1].y& 0xFFFF0000u);
      pk_.w = (ra[2*kc+1].z>>16) | (ra[2*kc+1].w& 0xFFFF0000u);
      af[kc] = __builtin_bit_cast(bf16x8, pk_);
    }

    f32x4 acc0={0,0,0,0}, acc1={0,0,0,0}, acc2={0,0,0,0}, acc3={0,0,0,0};
    #pragma unroll
    for(int kc=0;kc<16;kc++){
      bf16x8 w0 = *(const bf16x8*)(const void*)&wlds[((0*16+kc)*64 + lane)*8];
      bf16x8 w1 = *(const bf16x8*)(const void*)&wlds[((1*16+kc)*64 + lane)*8];
      bf16x8 w2 = *(const bf16x8*)(const void*)&wlds[((2*16+kc)*64 + lane)*8];
      bf16x8 w3 = *(const bf16x8*)(const void*)&wlds[((3*16+kc)*64 + lane)*8];
      acc0 = __builtin_amdgcn_mfma_f32_16x16x32_bf16(af[kc], w0, acc0, 0,0,0);
      acc1 = __builtin_amdgcn_mfma_f32_16x16x32_bf16(af[kc], w1, acc1, 0,0,0);
      acc2 = __builtin_amdgcn_mfma_f32_16x16x32_bf16(af[kc], w2, acc2, 0,0,0);
      acc3 = __builtin_amdgcn_mfma_f32_16x16x32_bf16(af[kc], w3, acc3, 0,0,0);
    }

    unsigned hv[4]; unsigned short hb16[4];
    int sc = s>>4, sl = s&15;
    unsigned tagw = (unsigned)(s+1);
    #pragma unroll
    for(int q=0;q<4;q++){
      int tok = tokbase[(mh*16 + rl0 + q)*TSEQ + s];
      const float* tbl = table + (size_t)tok*GATES;
      float zi = acc0[q] + tbl[j];
      float zf = acc1[q] + tbl[512+j];
      float zg = acc2[q] + tbl[1024+j];
      float zo = acc3[q] + tbl[1536+j];
      float cn = sigf(zf)*cst[q] + sigf(zi)*tanhfast(zg);
      float h  = sigf(zo)*tanhfast(cn);
      cst[q] = cn;
      unsigned short hbv = f2bf(h);
      hb16[q] = hbv;
      hv[q] = ((unsigned)hbv<<16) | tagw;
    }
    // publish tagged dwords; NO drain — tags self-validate at consumers
    asm volatile(
      "global_store_dword %[a], %[d0], %[sb] sc0 sc1\n\t"
      "global_store_dword %[a], %[d1], %[sb] offset:32 sc0 sc1\n\t"
      "global_store_dword %[a], %[d2], %[sb] offset:64 sc0 sc1\n\t"
      "global_store_dword %[a], %[d3], %[sb] offset:96 sc0 sc1"
      :: [a]"v"(pub_vo), [d0]"v"(hv[0]),[d1]"v"(hv[1]),[d2]"v"(hv[2]),[d3]"v"(hv[3]),
         [sb]"s"((void*)hout)
      : "memory");
    // archive h (cached, off critical path)
    #pragma unroll
    for(int q=0;q<4;q++){
      int r = rbase + q;
      int mc = r*32 + sc;
      hsb[((size_t)(mc*16 + kc_o)*64 + (sl|(hi<<4)))*8 + e_o] = hb16[q];
    }
  }
}

// z = hsb @ W_out + b_out  (bf16 MFMA). Writes z fp32 + bf16 frags for theta.
__global__ __launch_bounds__(256) void zproj_mfma(const unsigned short* __restrict__ hsb,
        const unsigned short* __restrict__ woutswz, const float* __restrict__ b_out,
        float* __restrict__ z, unsigned short* __restrict__ zxA, unsigned short* __restrict__ zyB){
  int tid = threadIdx.x, wv = tid>>6, lane = tid&63;
  int m0 = blockIdx.x*128 + (wv>>1)*64;
  int n0 = blockIdx.y*128 + (wv&1)*64;
  int mc0 = m0>>4, nc0 = n0>>4;
  const uint4* ha = (const uint4*)hsb;
  const uint4* wb = (const uint4*)woutswz;
  f32x4 acc[4][4];
  #pragma unroll
  for(int i=0;i<4;i++)
    #pragma unroll
    for(int k2=0;k2<4;k2++) acc[i][k2] = (f32x4){0,0,0,0};
  for(int kc=0;kc<16;kc++){
    bf16x8 a[4], b[4];
    #pragma unroll
    for(int i=0;i<4;i++){
      a[i] = __builtin_bit_cast(bf16x8, ha[((size_t)((mc0+i)*16 + kc))*64 + lane]);
      b[i] = __builtin_bit_cast(bf16x8, wb[((size_t)((nc0+i)*16 + kc))*64 + lane]);
    }
    #pragma unroll
    for(int mi=0;mi<4;mi++)
      #pragma unroll
      for(int ci=0;ci<4;ci++)
        acc[mi][ci] = __builtin_amdgcn_mfma_f32_16x16x32_bf16(a[mi], b[ci], acc[mi][ci], 0,0,0);
  }
  int r = m0>>9;
  bool isx = (r < NB);
  unsigned short* zb = isx ? zxA : zyB;
  int bb = isx ? r : r-NB;
  #pragma unroll
  for(int ci=0;ci<4;ci++){
    int n = n0 + ci*16 + (lane&15);
    float bo = b_out[n];
    int kcz = n>>5, hi = (n>>3)&3, ez = n&7;
    #pragma unroll
    for(int mi=0;mi<4;mi++){
      #pragma unroll
      for(int q=0;q<4;q++){
        int m = m0 + mi*16 + (lane>>4)*4 + q;
        float zv = acc[mi][ci][q] + bo;
        z[(size_t)m*EDIM + n] = zv;
        int i = m&511;
        zb[(((size_t)(bb*32 + (i>>4))*16 + kcz)*64 + ((i&15)|(hi<<4)))*8 + ez] = f2bf(zv);
      }
    }
  }
}

// theta in anti-diagonal layout: thetaD[b][i+j][i] = zx[b][i,:] . zy[b][j,:]
__global__ __launch_bounds__(256) void theta_mfma(const unsigned short* __restrict__ zxA,
        const unsigned short* __restrict__ zyB, float* __restrict__ thetaD){
  int tid = threadIdx.x, wv = tid>>6, lane = tid&63;
  int b = blockIdx.z;
  int i0 = blockIdx.x*128 + (wv>>1)*64;
  int j0 = blockIdx.y*128 + (wv&1)*64;
  int ic0 = i0>>4, jc0 = j0>>4;
  const uint4* pa = (const uint4*)zxA;
  const uint4* pb = (const uint4*)zyB;
  f32x4 acc[4][4];
  #pragma unroll
  for(int i=0;i<4;i++)
    #pragma unroll
    for(int k2=0;k2<4;k2++) acc[i][k2] = (f32x4){0,0,0,0};
  for(int kc=0;kc<16;kc++){
    bf16x8 a[4], bfr[4];
    #pragma unroll
    for(int i=0;i<4;i++){
      a[i]   = __builtin_bit_cast(bf16x8, pa[((size_t)(b*32 + ic0+i)*16 + kc)*64 + lane]);
      bfr[i] = __builtin_bit_cast(bf16x8, pb[((size_t)(b*32 + jc0+i)*16 + kc)*64 + lane]);
    }
    #pragma unroll
    for(int mi=0;mi<4;mi++)
      #pragma unroll
      for(int ci=0;ci<4;ci++)
        acc[mi][ci] = __builtin_amdgcn_mfma_f32_16x16x32_bf16(a[mi], bfr[ci], acc[mi][ci], 0,0,0);
  }
  #pragma unroll
  for(int mi=0;mi<4;mi++){
    #pragma unroll
    for(int ci=0;ci<4;ci++){
      #pragma unroll
      for(int q=0;q<4;q++){
        int i  = i0 + mi*16 + (lane>>4)*4 + q;
        int jj = j0 + ci*16 + (lane&15);
        thetaD[((size_t)b*1023 + (i+jj))*512 + i] = acc[mi][ci][q];
      }
    }
  }
}

__global__ __launch_bounds__(256) void mean_k(const float* __restrict__ z, float* __restrict__ zmean){
  int r = blockIdx.x;
  int tid = threadIdx.x;
  for(int ee=tid; ee<EDIM; ee+=256){
    float acc=0.f;
    for(int t=0;t<TSEQ;t++) acc += z[((size_t)r*TSEQ+t)*EDIM+ee];
    zmean[(size_t)r*EDIM+ee] = acc*(1.0f/TSEQ);
  }
}

__global__ __launch_bounds__(256) void gap_k(const float* __restrict__ zmean,
        const float* __restrict__ W_gap, const float* __restrict__ b_gap, float* __restrict__ Aout){
  __shared__ float red[256];
  int b = blockIdx.x;
  int tid = threadIdx.x;
  float acc=0.f;
  for(int i=tid;i<2*EDIM;i+=256){
    float m = (i<EDIM)? zmean[(size_t)b*EDIM+i] : zmean[(size_t)(b+NB)*EDIM + (i-EDIM)];
    acc = fmaf(m, W_gap[i], acc);
  }
  red[tid]=acc; __syncthreads();
  for(int s=128;s>0;s>>=1){ if(tid<s) red[tid]+=red[tid+s]; __syncthreads(); }
  if(tid==0) Aout[b] = red[0] + b_gap[0];
}

// NW: one wave per batch; diagonal-major theta -> coalesced float4 loads,
// next-diagonal prefetch overlaps DP math.
__global__ __launch_bounds__(64) void nw_k(const float* __restrict__ thetaD,
        const float* __restrict__ Aout, float* __restrict__ out){
  const float L2E = 1.4426950408889634f, LN2 = 0.6931471805599453f;
  int b = blockIdx.x;
  int lane = threadIdx.x;
  float A = Aout[b];
  const float* thD = thetaD + (size_t)b*1023*512;
  float p1[8], p2[8];
  #pragma unroll
  for(int i=0;i<8;i++){ p1[i]=NEGV; p2[i]=NEGV; }
  float p1_0 = NEGV, p2_0 = 0.0f;
  float4 ta = *(const float4*)&thD[(size_t)lane*8];
  float4 tb = *(const float4*)&thD[(size_t)lane*8+4];
  for(int k=2;k<=1024;k++){
    float4 na, nb;
    if(k<1024){
      na = *(const float4*)&thD[(size_t)(k-1)*512 + lane*8];
      nb = *(const float4*)&thD[(size_t)(k-1)*512 + lane*8+4];
    }
    float pm1 = __shfl_up(p1[7],1);
    float pm2 = __shfl_up(p2[7],1);
    if(lane==0){ pm1 = p1_0; pm2 = p2_0; }
    float td[8] = {ta.x,ta.y,ta.z,ta.w,tb.x,tb.y,tb.z,tb.w};
    float cur[8];
    #pragma unroll
    for(int cx=0;cx<8;cx++){
      int i = lane*8+1+cx;
      int jq = k-i;
      bool valid = (jq>=1)&&(jq<=512);
      float a  = (cx==0? pm1 : p1[cx-1]) + A;
      float bb = (cx==0? pm2 : p2[cx-1]);
      float cc = p1[cx] + A;
      float m = fmaxf(fmaxf(a,bb),cc);
      float sum = exp2f((a-m)*L2E) + exp2f((bb-m)*L2E) + exp2f((cc-m)*L2E);
      float v = m + log2f(sum)*LN2;
      cur[cx] = valid ? td[cx] + v : NEGV;
    }
    #pragma unroll
    for(int cx=0;cx<8;cx++){ p2[cx]=p1[cx]; p1[cx]=cur[cx]; }
    p2_0 = p1_0; p1_0 = NEGV;
    ta = na; tb = nb;
  }
  if(lane==63) out[b] = p1[7];
}

extern "C" void kernel_launch(void* const* d_in, const int* in_sizes, int n_in,
                              void* d_out, int out_size, void* d_ws, size_t ws_size,
                              hipStream_t stream) {
  (void)in_sizes; (void)n_in; (void)out_size; (void)ws_size;
  const int*   x      = (const int*)d_in[0];
  const int*   y      = (const int*)d_in[1];
  const float* emb    = (const float*)d_in[2];
  const float* W_ih   = (const float*)d_in[3];
  const float* W_hh   = (const float*)d_in[4];
  const float* b_lstm = (const float*)d_in[5];
  const float* W_out  = (const float*)d_in[6];
  const float* b_out  = (const float*)d_in[7];
  const float* W_gap  = (const float*)d_in[8];
  const float* b_gap  = (const float*)d_in[9];
  float* out = (float*)d_out;

  char* ws = (char*)d_ws;
  const size_t OFF_TABLE = 0;                         // 180224 (pad 184320)
  const size_t OFF_WSWZ  = 184320;                    // 2MB
  const size_t OFF_WOUT  = OFF_WSWZ  + 2097152;       // 512KB
  const size_t OFF_HX    = OFF_WOUT  + 524288;        // 256KB tagged h exchange
  const size_t OFF_HSB   = OFF_HX    + 262144;        // 32MB
  const size_t OFF_Z     = OFF_HSB   + 33554432;      // 64MB
  const size_t OFF_ZXA   = OFF_Z     + 67108864;      // 16MB
  const size_t OFF_ZYB   = OFF_ZXA   + 16777216;      // 16MB
  const size_t OFF_THD   = OFF_ZYB   + 16777216;      // 64MB (32x1023x512 f32)
  const size_t OFF_ZMEAN = OFF_THD   + 67043328;      // 128KB
  const size_t OFF_AOUT  = OFF_ZMEAN + 131072;        // 128B
  float* table = (float*)(ws + OFF_TABLE);
  unsigned short* Wswz    = (unsigned short*)(ws + OFF_WSWZ);
  unsigned short* woutswz = (unsigned short*)(ws + OFF_WOUT);
  unsigned* hx = (unsigned*)(ws + OFF_HX);
  unsigned short* hsb = (unsigned short*)(ws + OFF_HSB);
  float* z     = (float*)(ws + OFF_Z);
  unsigned short* zxA = (unsigned short*)(ws + OFF_ZXA);
  unsigned short* zyB = (unsigned short*)(ws + OFF_ZYB);
  float* thetaD = (float*)(ws + OFF_THD);
  float* zmean = (float*)(ws + OFF_ZMEAN);
  float* Aout  = (float*)(ws + OFF_AOUT);

  hipMemsetAsync(hx, 0, 262144, stream);   // h(0)=0 with tag 0, both parities

  table_k<<<dim3(8,22), 256, 0, stream>>>(emb, W_ih, b_lstm, table);
  wprep_k<<<2048, 64, 0, stream>>>(W_hh, Wswz);
  wprep2_k<<<512, 64, 0, stream>>>(W_out, woutswz);
  lstm_wave<<<128, 64, 0, stream>>>(x, y, table, Wswz, hx, hsb);
  zproj_mfma<<<dim3(256,4), 256, 0, stream>>>(hsb, woutswz, b_out, z, zxA, zyB);
  theta_mfma<<<dim3(4,4,32), 256, 0, stream>>>(zxA, zyB, thetaD);
  mean_k<<<64, 256, 0, stream>>>(z, zmean);
  gap_k<<<32, 256, 0, stream>>>(zmean, W_gap, b_gap, Aout);
  nw_k<<<32, 64, 0, stream>>>(thetaD, Aout, out);
}